// Round 1
// baseline (583.843 us; speedup 1.0000x reference)
//
#include <hip/hip_runtime.h>

#define NROWS 50000
#define NFEAT 512
#define NEDGE 1600000
#define SLOPE 0.01f

typedef unsigned short u16;
typedef __attribute__((ext_vector_type(8))) short short8;
typedef __attribute__((ext_vector_type(4))) float f32x4;
typedef __attribute__((ext_vector_type(8))) unsigned short u16x8;

__device__ __forceinline__ u16 f2bf(float f) {
  unsigned u = __float_as_uint(f);
  u += 0x7fffu + ((u >> 16) & 1u);
  return (u16)(u >> 16);
}
__device__ __forceinline__ float bf2f(u16 s) { return __uint_as_float(((unsigned)s) << 16); }
__device__ __forceinline__ float lrelu(float v) { return v >= 0.f ? v : SLOPE * v; }

__device__ __forceinline__ void gload_lds16(const u16* g, u16* l) {
  __builtin_amdgcn_global_load_lds((const __attribute__((address_space(1))) void*)g,
                                   (__attribute__((address_space(3))) void*)l, 16, 0, 0);
}

// ---------------- prep: xd = bf16(x * mask), wb = bf16(W) ----------------
__global__ void prep_xd_kernel(const float* __restrict__ x, const float* __restrict__ m,
                               u16* __restrict__ xd, int n8) {
  int stride = gridDim.x * blockDim.x;
  for (int i = blockIdx.x * blockDim.x + threadIdx.x; i < n8; i += stride) {
    size_t b = (size_t)i * 2;
    float4 a0 = ((const float4*)x)[b], a1 = ((const float4*)x)[b + 1];
    float4 m0 = ((const float4*)m)[b], m1 = ((const float4*)m)[b + 1];
    u16x8 o;
    o[0] = f2bf(a0.x * m0.x); o[1] = f2bf(a0.y * m0.y);
    o[2] = f2bf(a0.z * m0.z); o[3] = f2bf(a0.w * m0.w);
    o[4] = f2bf(a1.x * m1.x); o[5] = f2bf(a1.y * m1.y);
    o[6] = f2bf(a1.z * m1.z); o[7] = f2bf(a1.w * m1.w);
    *(u16x8*)(xd + (size_t)i * 8) = o;
  }
}

__global__ void prep_w_kernel(const float* __restrict__ w, u16* __restrict__ wb, int n8) {
  int stride = gridDim.x * blockDim.x;
  for (int i = blockIdx.x * blockDim.x + threadIdx.x; i < n8; i += stride) {
    size_t b = (size_t)i * 2;
    float4 a0 = ((const float4*)w)[b], a1 = ((const float4*)w)[b + 1];
    u16x8 o;
    o[0] = f2bf(a0.x); o[1] = f2bf(a0.y); o[2] = f2bf(a0.z); o[3] = f2bf(a0.w);
    o[4] = f2bf(a1.x); o[5] = f2bf(a1.y); o[6] = f2bf(a1.z); o[7] = f2bf(a1.w);
    *(u16x8*)(wb + (size_t)i * 8) = o;
  }
}

// ---------------- CSR build ----------------
__global__ void hist_kernel(const int* __restrict__ rows, int* __restrict__ counts) {
  int stride = gridDim.x * blockDim.x;
  for (int e = blockIdx.x * blockDim.x + threadIdx.x; e < NEDGE; e += stride)
    atomicAdd(&counts[rows[e]], 1);
}

__global__ void scan_kernel(const int* __restrict__ counts, int* __restrict__ offs) {
  __shared__ int sums[1024];
  int t = threadIdx.x;
  const int CH = (NROWS + 1023) / 1024;
  int beg = t * CH, end = beg + CH;
  if (end > NROWS) end = NROWS;
  if (beg > NROWS) beg = NROWS;
  int s = 0;
  for (int i = beg; i < end; ++i) s += counts[i];
  sums[t] = s;
  __syncthreads();
  if (t == 0) {
    int run = 0;
    for (int i = 0; i < 1024; ++i) { int v = sums[i]; sums[i] = run; run += v; }
    offs[NROWS] = run;
  }
  __syncthreads();
  int run = sums[t];
  for (int i = beg; i < end; ++i) { offs[i] = run; run += counts[i]; }
}

__global__ void scatter_kernel(const float* __restrict__ vals, const int* __restrict__ rows,
                               const int* __restrict__ cols, const int* __restrict__ offs,
                               int* __restrict__ cursor, float* __restrict__ sv,
                               int* __restrict__ sc) {
  int stride = gridDim.x * blockDim.x;
  for (int e = blockIdx.x * blockDim.x + threadIdx.x; e < NEDGE; e += stride) {
    int r = rows[e];
    int p = offs[r] + atomicAdd(&cursor[r], 1);
    sv[p] = vals[e];
    sc[p] = cols[e];
  }
}

// ---------------- GEMM: h = bf16(lrelu(xd @ wb^T)), 128x128 tile, bf16 MFMA ----------------
__global__ __launch_bounds__(256) void gemm_kernel(const u16* __restrict__ xd,
                                                   const u16* __restrict__ wb,
                                                   u16* __restrict__ h) {
  __shared__ __align__(16) u16 lA[128 * 32];
  __shared__ __align__(16) u16 lB[128 * 32];
  const int tid = threadIdx.x;
  const int lane = tid & 63;
  const int wid = tid >> 6;
  const int wm = wid >> 1, wn = wid & 1;
  const int bx = blockIdx.x;
  const int tm = bx >> 2;  // 391 M-tiles
  const int tn = bx & 3;   // 4 N-tiles
  const long rowBase = (long)tm * 128;

  f32x4 acc[4][4] = {};

  const int srow = lane >> 2;        // 0..15 row within 16-row staging chunk
  const int skoff = (lane & 3) * 8;  // bf16 offset within row (16B granules)

  for (int k0 = 0; k0 < 512; k0 += 32) {
    __syncthreads();
#pragma unroll
    for (int i = 0; i < 2; ++i) {
      int rowA = wid * 32 + i * 16 + srow;
      long gr = rowBase + rowA;
      if (gr > NROWS - 1) gr = NROWS - 1;  // clamp for partial last M-tile
      gload_lds16(xd + gr * 512 + k0 + skoff, lA + (wid * 32 + i * 16) * 32);
      int rowB = wid * 32 + i * 16 + srow;
      gload_lds16(wb + ((long)tn * 128 + rowB) * 512 + k0 + skoff,
                  lB + (wid * 32 + i * 16) * 32);
    }
    __syncthreads();
    short8 a[4], b[4];
    const int rsel = lane & 15, ksel = (lane >> 4) * 8;
#pragma unroll
    for (int m = 0; m < 4; ++m)
      a[m] = *(const short8*)(lA + (wm * 64 + m * 16 + rsel) * 32 + ksel);
#pragma unroll
    for (int n = 0; n < 4; ++n)
      b[n] = *(const short8*)(lB + (wn * 64 + n * 16 + rsel) * 32 + ksel);
#pragma unroll
    for (int m = 0; m < 4; ++m)
#pragma unroll
      for (int n = 0; n < 4; ++n)
        acc[m][n] = __builtin_amdgcn_mfma_f32_16x16x32_bf16(a[m], b[n], acc[m][n], 0, 0, 0);
  }

  const int crow = (lane >> 4) * 4;
  const int ccol = lane & 15;
#pragma unroll
  for (int m = 0; m < 4; ++m) {
    long row0 = rowBase + wm * 64 + m * 16 + crow;
#pragma unroll
    for (int n = 0; n < 4; ++n) {
      int col = tn * 128 + wn * 64 + n * 16 + ccol;
#pragma unroll
      for (int r2 = 0; r2 < 4; ++r2) {
        long rr = row0 + r2;
        if (rr < NROWS) h[rr * 512 + col] = f2bf(lrelu(acc[m][n][r2]));
      }
    }
  }
}

// ---------------- aggregate: one block per row, register accumulate ----------------
__global__ __launch_bounds__(256) void aggregate_kernel(const u16* __restrict__ h,
                                                        const float* __restrict__ sv,
                                                        const int* __restrict__ sc,
                                                        const int* __restrict__ offs,
                                                        float* __restrict__ out) {
  __shared__ float lv[256];
  __shared__ int lc[256];
  int r = blockIdx.x;
  int t = threadIdx.x;
  int beg = offs[r], end = offs[r + 1];
  float ax = 0.f, ay = 0.f;
  for (int base = beg; base < end; base += 256) {
    int n = end - base;
    if (n > 256) n = 256;
    __syncthreads();
    if (t < n) {
      lv[t] = sv[base + t];
      lc[t] = sc[base + t];
    }
    __syncthreads();
    for (int j = 0; j < n; ++j) {
      float v = lv[j];
      size_t c = (size_t)lc[j];
      ushort2 hh = *(const ushort2*)(h + c * NFEAT + 2 * t);
      ax += v * bf2f(hh.x);
      ay += v * bf2f(hh.y);
    }
  }
  float2 o;
  o.x = lrelu(ax);
  o.y = lrelu(ay);
  *(float2*)(out + (size_t)r * NFEAT + 2 * t) = o;
}

extern "C" void kernel_launch(void* const* d_in, const int* in_sizes, int n_in,
                              void* d_out, int out_size, void* d_ws, size_t ws_size,
                              hipStream_t stream) {
  const float* x = (const float*)d_in[0];
  const float* W = (const float*)d_in[1];
  const float* mask = (const float*)d_in[2];
  const float* vals = (const float*)d_in[3];
  const int* rows = (const int*)d_in[4];
  const int* cols = (const int*)d_in[5];
  float* out = (float*)d_out;
  char* ws = (char*)d_ws;

  // workspace layout (bytes)
  const size_t o_xd = 0;                          // 50000*512*2 = 51,200,000
  const size_t o_h = o_xd + 51200000;             // 51,200,000
  const size_t o_wb = o_h + 51200000;             // 524,288
  const size_t o_counts = o_wb + 524288;          // 200,000
  const size_t o_cursor = o_counts + 200000;      // 200,000 (contiguous w/ counts for one memset)
  const size_t o_offs = o_cursor + 200000;        // 200,004 (pad to 200,064)
  const size_t o_sv = o_offs + 200064;            // 6,400,000
  const size_t o_sc = o_sv + 6400000;             // 6,400,000
  // total ~116.3 MB

  u16* xd = (u16*)(ws + o_xd);
  u16* h = (u16*)(ws + o_h);
  u16* wb = (u16*)(ws + o_wb);
  int* counts = (int*)(ws + o_counts);
  int* cursor = (int*)(ws + o_cursor);
  int* offs = (int*)(ws + o_offs);
  float* sv = (float*)(ws + o_sv);
  int* sc = (int*)(ws + o_sc);

  hipMemsetAsync(counts, 0, 400000, stream);  // counts + cursor

  prep_xd_kernel<<<2048, 256, 0, stream>>>(x, mask, xd, (NROWS * NFEAT) / 8);
  prep_w_kernel<<<128, 256, 0, stream>>>(W, wb, (NFEAT * NFEAT) / 8);
  hist_kernel<<<2048, 256, 0, stream>>>(rows, counts);
  scan_kernel<<<1, 1024, 0, stream>>>(counts, offs);
  scatter_kernel<<<2048, 256, 0, stream>>>(vals, rows, cols, offs, cursor, sv, sc);
  gemm_kernel<<<391 * 4, 256, 0, stream>>>(xd, wb, h);
  aggregate_kernel<<<NROWS, 256, 0, stream>>>(h, sv, sc, offs, out);
}

// Round 2
// 553.219 us; speedup vs baseline: 1.0554x; 1.0554x over previous
//
#include <hip/hip_runtime.h>

#define NROWS 50000
#define NFEAT 512
#define NEDGE 1600000
#define SLOPE 0.01f

typedef unsigned short u16;
typedef __attribute__((ext_vector_type(8))) short short8;
typedef __attribute__((ext_vector_type(4))) float f32x4;
typedef __attribute__((ext_vector_type(8))) unsigned short u16x8;

__device__ __forceinline__ u16 f2bf(float f) {
  unsigned u = __float_as_uint(f);
  u += 0x7fffu + ((u >> 16) & 1u);
  return (u16)(u >> 16);
}
__device__ __forceinline__ float bf2f(u16 s) { return __uint_as_float(((unsigned)s) << 16); }
__device__ __forceinline__ float lrelu(float v) { return v >= 0.f ? v : SLOPE * v; }

__device__ __forceinline__ void gload_lds16(const u16* g, u16* l) {
  __builtin_amdgcn_global_load_lds((const __attribute__((address_space(1))) void*)g,
                                   (__attribute__((address_space(3))) void*)l, 16, 0, 0);
}

// ---- fused prep: xd = bf16(x*mask), wb = bf16(W), counts = row histogram ----
__global__ void prep_kernel(const float* __restrict__ x, const float* __restrict__ m,
                            u16* __restrict__ xd, const float* __restrict__ w,
                            u16* __restrict__ wb, const int* __restrict__ rows,
                            int* __restrict__ counts) {
  const int stride = gridDim.x * blockDim.x;
  const int tid0 = blockIdx.x * blockDim.x + threadIdx.x;
  for (int i = tid0; i < (NROWS * NFEAT) / 8; i += stride) {
    size_t b = (size_t)i * 2;
    float4 a0 = ((const float4*)x)[b], a1 = ((const float4*)x)[b + 1];
    float4 m0 = ((const float4*)m)[b], m1 = ((const float4*)m)[b + 1];
    u16x8 o;
    o[0] = f2bf(a0.x * m0.x); o[1] = f2bf(a0.y * m0.y);
    o[2] = f2bf(a0.z * m0.z); o[3] = f2bf(a0.w * m0.w);
    o[4] = f2bf(a1.x * m1.x); o[5] = f2bf(a1.y * m1.y);
    o[6] = f2bf(a1.z * m1.z); o[7] = f2bf(a1.w * m1.w);
    *(u16x8*)(xd + (size_t)i * 8) = o;
  }
  for (int i = tid0; i < (NFEAT * NFEAT) / 8; i += stride) {
    size_t b = (size_t)i * 2;
    float4 a0 = ((const float4*)w)[b], a1 = ((const float4*)w)[b + 1];
    u16x8 o;
    o[0] = f2bf(a0.x); o[1] = f2bf(a0.y); o[2] = f2bf(a0.z); o[3] = f2bf(a0.w);
    o[4] = f2bf(a1.x); o[5] = f2bf(a1.y); o[6] = f2bf(a1.z); o[7] = f2bf(a1.w);
    *(u16x8*)(wb + (size_t)i * 8) = o;
  }
  for (int e = tid0; e < NEDGE; e += stride) atomicAdd(&counts[rows[e]], 1);
}

// ---- scan: wave shfl-scan of 1024 partials, 16-entry serial combine ----
__global__ void scan_kernel(const int* __restrict__ counts, int* __restrict__ offs) {
  __shared__ int wpre[17];
  const int t = threadIdx.x;            // 1024 threads
  const int lane = t & 63, w = t >> 6;  // 16 waves
  const int CH = (NROWS + 1023) / 1024; // 49
  int beg = t * CH; if (beg > NROWS) beg = NROWS;
  int end = beg + CH; if (end > NROWS) end = NROWS;
  int s = 0;
  for (int i = beg; i < end; ++i) s += counts[i];
  int inc = s;
#pragma unroll
  for (int d = 1; d < 64; d <<= 1) {
    int u = __shfl_up(inc, d);
    if (lane >= d) inc += u;
  }
  if (lane == 63) wpre[w + 1] = inc;
  __syncthreads();
  if (t == 0) {
    wpre[0] = 0;
    for (int i = 1; i <= 16; ++i) wpre[i] += wpre[i - 1];
    offs[NROWS] = wpre[16];
  }
  __syncthreads();
  int run = wpre[w] + inc - s;  // exclusive prefix for this thread
  for (int i = beg; i < end; ++i) { offs[i] = run; run += counts[i]; }
}

__global__ void scatter_kernel(const float* __restrict__ vals, const int* __restrict__ rows,
                               const int* __restrict__ cols, const int* __restrict__ offs,
                               int* __restrict__ cursor, float* __restrict__ sv,
                               int* __restrict__ sc) {
  int stride = gridDim.x * blockDim.x;
  for (int e = blockIdx.x * blockDim.x + threadIdx.x; e < NEDGE; e += stride) {
    int r = rows[e];
    int p = offs[r] + atomicAdd(&cursor[r], 1);
    sv[p] = vals[e];
    sc[p] = cols[e];
  }
}

// ---- GEMM: h = bf16(lrelu(xd @ wb^T)), 128x128 tile, bf16 MFMA ----
__global__ __launch_bounds__(256) void gemm_kernel(const u16* __restrict__ xd,
                                                   const u16* __restrict__ wb,
                                                   u16* __restrict__ h) {
  __shared__ __align__(16) u16 lA[128 * 32];
  __shared__ __align__(16) u16 lB[128 * 32];
  const int tid = threadIdx.x;
  const int lane = tid & 63;
  const int wid = tid >> 6;
  const int wm = wid >> 1, wn = wid & 1;
  const int bx = blockIdx.x;
  const int tm = bx >> 2;
  const int tn = bx & 3;
  const long rowBase = (long)tm * 128;

  f32x4 acc[4][4] = {};

  const int srow = lane >> 2;
  const int skoff = (lane & 3) * 8;

  for (int k0 = 0; k0 < 512; k0 += 32) {
    __syncthreads();
#pragma unroll
    for (int i = 0; i < 2; ++i) {
      int rowA = wid * 32 + i * 16 + srow;
      long gr = rowBase + rowA;
      if (gr > NROWS - 1) gr = NROWS - 1;
      gload_lds16(xd + gr * 512 + k0 + skoff, lA + (wid * 32 + i * 16) * 32);
      int rowB = wid * 32 + i * 16 + srow;
      gload_lds16(wb + ((long)tn * 128 + rowB) * 512 + k0 + skoff,
                  lB + (wid * 32 + i * 16) * 32);
    }
    __syncthreads();
    short8 a[4], b[4];
    const int rsel = lane & 15, ksel = (lane >> 4) * 8;
#pragma unroll
    for (int m = 0; m < 4; ++m)
      a[m] = *(const short8*)(lA + (wm * 64 + m * 16 + rsel) * 32 + ksel);
#pragma unroll
    for (int n = 0; n < 4; ++n)
      b[n] = *(const short8*)(lB + (wn * 64 + n * 16 + rsel) * 32 + ksel);
#pragma unroll
    for (int m = 0; m < 4; ++m)
#pragma unroll
      for (int n = 0; n < 4; ++n)
        acc[m][n] = __builtin_amdgcn_mfma_f32_16x16x32_bf16(a[m], b[n], acc[m][n], 0, 0, 0);
  }

  const int crow = (lane >> 4) * 4;
  const int ccol = lane & 15;
#pragma unroll
  for (int m = 0; m < 4; ++m) {
    long row0 = rowBase + wm * 64 + m * 16 + crow;
#pragma unroll
    for (int n = 0; n < 4; ++n) {
      int col = tn * 128 + wn * 64 + n * 16 + ccol;
#pragma unroll
      for (int r2 = 0; r2 < 4; ++r2) {
        long rr = row0 + r2;
        if (rr < NROWS) h[rr * 512 + col] = f2bf(lrelu(acc[m][n][r2]));
      }
    }
  }
}

// ---- aggregate: one WAVE per row, 16B/lane gathers, x4 edge unroll ----
__global__ __launch_bounds__(256) void aggregate_kernel(const u16* __restrict__ h,
                                                        const float* __restrict__ sv,
                                                        const int* __restrict__ sc,
                                                        const int* __restrict__ offs,
                                                        float* __restrict__ out) {
  const int lane = threadIdx.x & 63;
  const int wid = threadIdx.x >> 6;
  const int r = blockIdx.x * 4 + wid;
  if (r >= NROWS) return;
  const int beg = offs[r], end = offs[r + 1];
  float a[8] = {};
  const u16* hp = h + lane * 8;
  int e = beg;
  for (; e + 4 <= end; e += 4) {
    int c0 = sc[e], c1 = sc[e + 1], c2 = sc[e + 2], c3 = sc[e + 3];
    float v0 = sv[e], v1 = sv[e + 1], v2 = sv[e + 2], v3 = sv[e + 3];
    u16x8 H0 = *(const u16x8*)(hp + (size_t)c0 * NFEAT);
    u16x8 H1 = *(const u16x8*)(hp + (size_t)c1 * NFEAT);
    u16x8 H2 = *(const u16x8*)(hp + (size_t)c2 * NFEAT);
    u16x8 H3 = *(const u16x8*)(hp + (size_t)c3 * NFEAT);
#pragma unroll
    for (int k = 0; k < 8; ++k)
      a[k] += v0 * bf2f(H0[k]) + v1 * bf2f(H1[k]) + v2 * bf2f(H2[k]) + v3 * bf2f(H3[k]);
  }
  for (; e < end; ++e) {
    int c = sc[e];
    float v = sv[e];
    u16x8 H = *(const u16x8*)(hp + (size_t)c * NFEAT);
#pragma unroll
    for (int k = 0; k < 8; ++k) a[k] += v * bf2f(H[k]);
  }
  float* op = out + (size_t)r * NFEAT + lane * 8;
  float4 o0, o1;
  o0.x = lrelu(a[0]); o0.y = lrelu(a[1]); o0.z = lrelu(a[2]); o0.w = lrelu(a[3]);
  o1.x = lrelu(a[4]); o1.y = lrelu(a[5]); o1.z = lrelu(a[6]); o1.w = lrelu(a[7]);
  *(float4*)op = o0;
  *(float4*)(op + 4) = o1;
}

extern "C" void kernel_launch(void* const* d_in, const int* in_sizes, int n_in,
                              void* d_out, int out_size, void* d_ws, size_t ws_size,
                              hipStream_t stream) {
  const float* x = (const float*)d_in[0];
  const float* W = (const float*)d_in[1];
  const float* mask = (const float*)d_in[2];
  const float* vals = (const float*)d_in[3];
  const int* rows = (const int*)d_in[4];
  const int* cols = (const int*)d_in[5];
  float* out = (float*)d_out;
  char* ws = (char*)d_ws;

  const size_t o_xd = 0;
  const size_t o_h = o_xd + 51200000;
  const size_t o_wb = o_h + 51200000;
  const size_t o_counts = o_wb + 524288;
  const size_t o_cursor = o_counts + 200000;
  const size_t o_offs = o_cursor + 200000;
  const size_t o_sv = o_offs + 200064;
  const size_t o_sc = o_sv + 6400000;

  u16* xd = (u16*)(ws + o_xd);
  u16* h = (u16*)(ws + o_h);
  u16* wb = (u16*)(ws + o_wb);
  int* counts = (int*)(ws + o_counts);
  int* cursor = (int*)(ws + o_cursor);
  int* offs = (int*)(ws + o_offs);
  float* sv = (float*)(ws + o_sv);
  int* sc = (int*)(ws + o_sc);

  hipMemsetAsync(counts, 0, 400000, stream);  // counts + cursor

  prep_kernel<<<2048, 256, 0, stream>>>(x, mask, xd, W, wb, rows, counts);
  scan_kernel<<<1, 1024, 0, stream>>>(counts, offs);
  scatter_kernel<<<2048, 256, 0, stream>>>(vals, rows, cols, offs, cursor, sv, sc);
  gemm_kernel<<<391 * 4, 256, 0, stream>>>(xd, wb, h);
  aggregate_kernel<<<12500, 256, 0, stream>>>(h, sv, sc, offs, out);
}

// Round 4
// 444.820 us; speedup vs baseline: 1.3125x; 1.2437x over previous
//
#include <hip/hip_runtime.h>

#define NROWS 50000
#define NFEAT 512
#define NEDGE 1600000
#define SLOPE 0.01f

typedef unsigned short u16;
typedef __attribute__((ext_vector_type(8))) short short8;
typedef __attribute__((ext_vector_type(4))) float f32x4;
typedef __attribute__((ext_vector_type(8))) unsigned short u16x8;

__device__ __forceinline__ u16 f2bf(float f) {
  unsigned u = __float_as_uint(f);
  u += 0x7fffu + ((u >> 16) & 1u);
  return (u16)(u >> 16);
}
__device__ __forceinline__ float lrelu(float v) { return v >= 0.f ? v : SLOPE * v; }

__device__ __forceinline__ void gload_lds16(const u16* g, u16* l) {
  __builtin_amdgcn_global_load_lds((const __attribute__((address_space(1))) void*)g,
                                   (__attribute__((address_space(3))) void*)l, 16, 0, 0);
}

// ---- fused prep: xd = bf16(x*mask), wb = bf16(W), counts = row histogram ----
__global__ void prep_kernel(const float* __restrict__ x, const float* __restrict__ m,
                            u16* __restrict__ xd, const float* __restrict__ w,
                            u16* __restrict__ wb, const int* __restrict__ rows,
                            int* __restrict__ counts) {
  const int stride = gridDim.x * blockDim.x;
  const int tid0 = blockIdx.x * blockDim.x + threadIdx.x;
  for (int i = tid0; i < (NROWS * NFEAT) / 8; i += stride) {
    size_t b = (size_t)i * 2;
    float4 a0 = ((const float4*)x)[b], a1 = ((const float4*)x)[b + 1];
    float4 m0 = ((const float4*)m)[b], m1 = ((const float4*)m)[b + 1];
    u16x8 o;
    o[0] = f2bf(a0.x * m0.x); o[1] = f2bf(a0.y * m0.y);
    o[2] = f2bf(a0.z * m0.z); o[3] = f2bf(a0.w * m0.w);
    o[4] = f2bf(a1.x * m1.x); o[5] = f2bf(a1.y * m1.y);
    o[6] = f2bf(a1.z * m1.z); o[7] = f2bf(a1.w * m1.w);
    *(u16x8*)(xd + (size_t)i * 8) = o;
  }
  for (int i = tid0; i < (NFEAT * NFEAT) / 8; i += stride) {
    size_t b = (size_t)i * 2;
    float4 a0 = ((const float4*)w)[b], a1 = ((const float4*)w)[b + 1];
    u16x8 o;
    o[0] = f2bf(a0.x); o[1] = f2bf(a0.y); o[2] = f2bf(a0.z); o[3] = f2bf(a0.w);
    o[4] = f2bf(a1.x); o[5] = f2bf(a1.y); o[6] = f2bf(a1.z); o[7] = f2bf(a1.w);
    *(u16x8*)(wb + (size_t)i * 8) = o;
  }
  for (int e = tid0; e < NEDGE; e += stride) atomicAdd(&counts[rows[e]], 1);
}

// ---- scan: wave shfl-scan of 1024 partials, 16-entry serial combine ----
__global__ void scan_kernel(const int* __restrict__ counts, int* __restrict__ offs) {
  __shared__ int wpre[17];
  const int t = threadIdx.x;
  const int lane = t & 63, w = t >> 6;
  const int CH = (NROWS + 1023) / 1024;
  int beg = t * CH; if (beg > NROWS) beg = NROWS;
  int end = beg + CH; if (end > NROWS) end = NROWS;
  int s = 0;
  for (int i = beg; i < end; ++i) s += counts[i];
  int inc = s;
#pragma unroll
  for (int d = 1; d < 64; d <<= 1) {
    int u = __shfl_up(inc, d);
    if (lane >= d) inc += u;
  }
  if (lane == 63) wpre[w + 1] = inc;
  __syncthreads();
  if (t == 0) {
    wpre[0] = 0;
    for (int i = 1; i <= 16; ++i) wpre[i] += wpre[i - 1];
    offs[NROWS] = wpre[16];
  }
  __syncthreads();
  int run = wpre[w] + inc - s;
  for (int i = beg; i < end; ++i) { offs[i] = run; run += counts[i]; }
}

// ---- scatter: pack (val, col) into one int2, single 8B random store per edge ----
__global__ void scatter_kernel(const float* __restrict__ vals, const int* __restrict__ rows,
                               const int* __restrict__ cols, const int* __restrict__ offs,
                               int* __restrict__ cursor, int2* __restrict__ svc) {
  int stride = gridDim.x * blockDim.x;
  for (int e = blockIdx.x * blockDim.x + threadIdx.x; e < NEDGE; e += stride) {
    int r = rows[e];
    int p = offs[r] + atomicAdd(&cursor[r], 1);
    int2 q;
    q.x = __float_as_int(vals[e]);
    q.y = cols[e];
    svc[p] = q;
  }
}

// ---- GEMM: hq = int8(lrelu(xd @ wb^T) / scale[row][tn]), per-(row,128col) scale ----
__global__ __launch_bounds__(256) void gemm_kernel(const u16* __restrict__ xd,
                                                   const u16* __restrict__ wb,
                                                   unsigned char* __restrict__ hq,
                                                   float* __restrict__ scaleg) {
  __shared__ __align__(16) u16 lAB[2 * 128 * 32];
  __shared__ float wmax[2][128];  // [wn][block-local row]
  __shared__ float rinv[128];
  u16* lA = lAB;
  u16* lB = lAB + 128 * 32;
  const int tid = threadIdx.x;
  const int lane = tid & 63;
  const int wid = tid >> 6;
  const int wm = wid >> 1, wn = wid & 1;
  const int bx = blockIdx.x;
  const int tm = bx >> 2;
  const int tn = bx & 3;
  const long rowBase = (long)tm * 128;

  f32x4 acc[4][4] = {};

  const int srow = lane >> 2;
  const int skoff = (lane & 3) * 8;

  for (int k0 = 0; k0 < 512; k0 += 32) {
    __syncthreads();
#pragma unroll
    for (int i = 0; i < 2; ++i) {
      int rowA = wid * 32 + i * 16 + srow;
      long gr = rowBase + rowA;
      if (gr > NROWS - 1) gr = NROWS - 1;
      gload_lds16(xd + gr * 512 + k0 + skoff, lA + (wid * 32 + i * 16) * 32);
      int rowB = wid * 32 + i * 16 + srow;
      gload_lds16(wb + ((long)tn * 128 + rowB) * 512 + k0 + skoff,
                  lB + (wid * 32 + i * 16) * 32);
    }
    __syncthreads();
    short8 a[4], b[4];
    const int rsel = lane & 15, ksel = (lane >> 4) * 8;
#pragma unroll
    for (int m = 0; m < 4; ++m)
      a[m] = *(const short8*)(lA + (wm * 64 + m * 16 + rsel) * 32 + ksel);
#pragma unroll
    for (int n = 0; n < 4; ++n)
      b[n] = *(const short8*)(lB + (wn * 64 + n * 16 + rsel) * 32 + ksel);
#pragma unroll
    for (int m = 0; m < 4; ++m)
#pragma unroll
      for (int n = 0; n < 4; ++n)
        acc[m][n] = __builtin_amdgcn_mfma_f32_16x16x32_bf16(a[m], b[n], acc[m][n], 0, 0, 0);
  }

  // ---- epilogue: per-row max -> scale, int8 quantize, LDS byte-transpose, 16B stores ----
  const int crow = (lane >> 4) * 4;
  const int ccol = lane & 15;

  // per-lane max over n frags: pm[m][r2], then 16-lane tree (lanes sharing rows)
  float pm[4][4];
#pragma unroll
  for (int m = 0; m < 4; ++m)
#pragma unroll
    for (int r2 = 0; r2 < 4; ++r2) {
      float mx = 0.f;
#pragma unroll
      for (int n = 0; n < 4; ++n) mx = fmaxf(mx, fabsf(lrelu(acc[m][n][r2])));
      pm[m][r2] = mx;
    }
#pragma unroll
  for (int d = 1; d < 16; d <<= 1)
#pragma unroll
    for (int m = 0; m < 4; ++m)
#pragma unroll
      for (int r2 = 0; r2 < 4; ++r2) pm[m][r2] = fmaxf(pm[m][r2], __shfl_xor(pm[m][r2], d));
  if ((lane & 15) == 0) {
#pragma unroll
    for (int m = 0; m < 4; ++m)
#pragma unroll
      for (int r2 = 0; r2 < 4; ++r2) wmax[wn][wm * 64 + m * 16 + crow + r2] = pm[m][r2];
  }
  __syncthreads();  // wmax ready AND all waves done reading lA/lB
  if (tid < 128) {
    float rm = fmaxf(wmax[0][tid], wmax[1][tid]);
    float s = rm > 0.f ? rm * (1.f / 127.f) : 1.f;
    rinv[tid] = rm > 0.f ? 127.f / rm : 0.f;
    long gr = rowBase + tid;
    if (gr < NROWS) scaleg[gr * 4 + tn] = s;
  }
  __syncthreads();

  unsigned char* lT = (unsigned char*)lAB;  // 128 x 128 int8 tile
#pragma unroll
  for (int m = 0; m < 4; ++m) {
    int row0 = wm * 64 + m * 16 + crow;
    float ri0 = rinv[row0], ri1 = rinv[row0 + 1], ri2 = rinv[row0 + 2], ri3 = rinv[row0 + 3];
#pragma unroll
    for (int n = 0; n < 4; ++n) {
      int col = wn * 64 + n * 16 + ccol;
      float q0 = rintf(lrelu(acc[m][n][0]) * ri0);
      float q1 = rintf(lrelu(acc[m][n][1]) * ri1);
      float q2 = rintf(lrelu(acc[m][n][2]) * ri2);
      float q3 = rintf(lrelu(acc[m][n][3]) * ri3);
      int i0 = min(127, max(-127, (int)q0));
      int i1 = min(127, max(-127, (int)q1));
      int i2 = min(127, max(-127, (int)q2));
      int i3 = min(127, max(-127, (int)q3));
      unsigned pk = (i0 & 0xff) | ((i1 & 0xff) << 8) | ((i2 & 0xff) << 16) | ((i3 & 0xff) << 24);
#pragma unroll
      for (int r2 = 0; r2 < 4; ++r2) {
        int row = row0 + r2;
        lT[row * 128 + (col ^ ((row & 7) << 4))] = (unsigned char)(pk >> (8 * r2));
      }
    }
  }
  __syncthreads();
  {
    const int row = tid >> 1, seg = tid & 1;
    long gr = rowBase + row;
    if (gr < NROWS) {
      unsigned char* dst = hq + gr * 512 + tn * 128;
#pragma unroll
      for (int j = 0; j < 4; ++j) {
        int s = seg * 4 + j;
        int4 vv = *(const int4*)(lT + row * 128 + ((s ^ (row & 7)) << 4));
        *(int4*)(dst + s * 16) = vv;
      }
    }
  }
}

// ---- aggregate: one WAVE per row, int8 gathers 8B/lane + per-group scale ----
__global__ __launch_bounds__(256) void aggregate_kernel(const unsigned char* __restrict__ hq,
                                                        const float* __restrict__ scaleg,
                                                        const int2* __restrict__ svc,
                                                        const int* __restrict__ offs,
                                                        float* __restrict__ out) {
  const int lane = threadIdx.x & 63;
  const int wid = threadIdx.x >> 6;
  const int r = blockIdx.x * 4 + wid;
  if (r >= NROWS) return;
  const int beg = offs[r], end = offs[r + 1];
  const int grp = lane >> 4;
  float a[8] = {};
  const unsigned char* hp = hq + lane * 8;
  int2 cb[8], nb[8];
  const int ng = (end - beg) >> 3;
  if (ng > 0) {
#pragma unroll
    for (int k = 0; k < 8; ++k) cb[k] = svc[beg + k];
  }
  for (int g = 0; g < ng; ++g) {
    if (g + 1 < ng) {
#pragma unroll
      for (int k = 0; k < 8; ++k) nb[k] = svc[beg + (g + 1) * 8 + k];
    }
#pragma unroll
    for (int k = 0; k < 8; ++k) {
      float v = __int_as_float(cb[k].x);
      size_t c = (size_t)cb[k].y;
      float vs = v * scaleg[c * 4 + grp];
      uint2 q = *(const uint2*)(hp + c * 512);
      a[0] += vs * (float)(signed char)(q.x);
      a[1] += vs * (float)(signed char)(q.x >> 8);
      a[2] += vs * (float)(signed char)(q.x >> 16);
      a[3] += vs * (float)(signed char)(q.x >> 24);
      a[4] += vs * (float)(signed char)(q.y);
      a[5] += vs * (float)(signed char)(q.y >> 8);
      a[6] += vs * (float)(signed char)(q.y >> 16);
      a[7] += vs * (float)(signed char)(q.y >> 24);
    }
    if (g + 1 < ng) {
#pragma unroll
      for (int k = 0; k < 8; ++k) cb[k] = nb[k];
    }
  }
  for (int e = beg + ng * 8; e < end; ++e) {
    int2 q2 = svc[e];
    float v = __int_as_float(q2.x);
    size_t c = (size_t)q2.y;
    float vs = v * scaleg[c * 4 + grp];
    uint2 q = *(const uint2*)(hp + c * 512);
    a[0] += vs * (float)(signed char)(q.x);
    a[1] += vs * (float)(signed char)(q.x >> 8);
    a[2] += vs * (float)(signed char)(q.x >> 16);
    a[3] += vs * (float)(signed char)(q.x >> 24);
    a[4] += vs * (float)(signed char)(q.y);
    a[5] += vs * (float)(signed char)(q.y >> 8);
    a[6] += vs * (float)(signed char)(q.y >> 16);
    a[7] += vs * (float)(signed char)(q.y >> 24);
  }
  float* op = out + (size_t)r * NFEAT + lane * 8;
  float4 o0, o1;
  o0.x = lrelu(a[0]); o0.y = lrelu(a[1]); o0.z = lrelu(a[2]); o0.w = lrelu(a[3]);
  o1.x = lrelu(a[4]); o1.y = lrelu(a[5]); o1.z = lrelu(a[6]); o1.w = lrelu(a[7]);
  *(float4*)op = o0;
  *(float4*)(op + 4) = o1;
}

extern "C" void kernel_launch(void* const* d_in, const int* in_sizes, int n_in,
                              void* d_out, int out_size, void* d_ws, size_t ws_size,
                              hipStream_t stream) {
  const float* x = (const float*)d_in[0];
  const float* W = (const float*)d_in[1];
  const float* mask = (const float*)d_in[2];
  const float* vals = (const float*)d_in[3];
  const int* rows = (const int*)d_in[4];
  const int* cols = (const int*)d_in[5];
  float* out = (float*)d_out;
  char* ws = (char*)d_ws;

  // workspace layout (bytes)
  const size_t o_xd = 0;                       // 51,200,000 (bf16 x*mask)
  const size_t o_hq = o_xd + 51200000;         // 25,600,000 (int8 h)
  const size_t o_wb = o_hq + 25600000;         // 524,288
  const size_t o_scale = o_wb + 524288;        // 800,000 (f32 scale[row][4])
  const size_t o_counts = o_scale + 800000;    // 200,000
  const size_t o_cursor = o_counts + 200000;   // 200,000
  const size_t o_offs = o_cursor + 200000;     // 200,064
  const size_t o_svc = o_offs + 200064;        // 12,800,000 (int2 packed val/col)
  // total ~91.5 MB

  u16* xd = (u16*)(ws + o_xd);
  unsigned char* hq = (unsigned char*)(ws + o_hq);
  u16* wb = (u16*)(ws + o_wb);
  float* scaleg = (float*)(ws + o_scale);
  int* counts = (int*)(ws + o_counts);
  int* cursor = (int*)(ws + o_cursor);
  int* offs = (int*)(ws + o_offs);
  int2* svc = (int2*)(ws + o_svc);

  hipMemsetAsync(counts, 0, 400000, stream);  // counts + cursor

  prep_kernel<<<2048, 256, 0, stream>>>(x, mask, xd, W, wb, rows, counts);
  scan_kernel<<<1, 1024, 0, stream>>>(counts, offs);
  scatter_kernel<<<2048, 256, 0, stream>>>(vals, rows, cols, offs, cursor, svc);
  gemm_kernel<<<391 * 4, 256, 0, stream>>>(xd, wb, hq, scaleg);
  aggregate_kernel<<<12500, 256, 0, stream>>>(hq, scaleg, svc, offs, out);
}

// Round 5
// 423.715 us; speedup vs baseline: 1.3779x; 1.0498x over previous
//
#include <hip/hip_runtime.h>

#define NROWS 50000
#define NFEAT 512
#define NEDGE 1600000
#define SLOPE 0.01f

typedef unsigned short u16;
typedef __attribute__((ext_vector_type(8))) short short8;
typedef __attribute__((ext_vector_type(4))) float f32x4;
typedef __attribute__((ext_vector_type(8))) unsigned short u16x8;

__device__ __forceinline__ u16 f2bf(float f) {
  unsigned u = __float_as_uint(f);
  u += 0x7fffu + ((u >> 16) & 1u);
  return (u16)(u >> 16);
}
__device__ __forceinline__ float lrelu(float v) { return v >= 0.f ? v : SLOPE * v; }

__device__ __forceinline__ void gload_lds16(const u16* g, u16* l) {
  __builtin_amdgcn_global_load_lds((const __attribute__((address_space(1))) void*)g,
                                   (__attribute__((address_space(3))) void*)l, 16, 0, 0);
}

// ---- fused prep: xd = bf16(x*mask), wb = bf16(W), counts = row histogram ----
__global__ void prep_kernel(const float* __restrict__ x, const float* __restrict__ m,
                            u16* __restrict__ xd, const float* __restrict__ w,
                            u16* __restrict__ wb, const int* __restrict__ rows,
                            int* __restrict__ counts) {
  const int stride = gridDim.x * blockDim.x;
  const int tid0 = blockIdx.x * blockDim.x + threadIdx.x;
  for (int i = tid0; i < (NROWS * NFEAT) / 8; i += stride) {
    size_t b = (size_t)i * 2;
    float4 a0 = ((const float4*)x)[b], a1 = ((const float4*)x)[b + 1];
    float4 m0 = ((const float4*)m)[b], m1 = ((const float4*)m)[b + 1];
    u16x8 o;
    o[0] = f2bf(a0.x * m0.x); o[1] = f2bf(a0.y * m0.y);
    o[2] = f2bf(a0.z * m0.z); o[3] = f2bf(a0.w * m0.w);
    o[4] = f2bf(a1.x * m1.x); o[5] = f2bf(a1.y * m1.y);
    o[6] = f2bf(a1.z * m1.z); o[7] = f2bf(a1.w * m1.w);
    *(u16x8*)(xd + (size_t)i * 8) = o;
  }
  for (int i = tid0; i < (NFEAT * NFEAT) / 8; i += stride) {
    size_t b = (size_t)i * 2;
    float4 a0 = ((const float4*)w)[b], a1 = ((const float4*)w)[b + 1];
    u16x8 o;
    o[0] = f2bf(a0.x); o[1] = f2bf(a0.y); o[2] = f2bf(a0.z); o[3] = f2bf(a0.w);
    o[4] = f2bf(a1.x); o[5] = f2bf(a1.y); o[6] = f2bf(a1.z); o[7] = f2bf(a1.w);
    *(u16x8*)(wb + (size_t)i * 8) = o;
  }
  for (int i = tid0; i < NEDGE / 4; i += stride) {
    int4 r4 = ((const int4*)rows)[i];
    atomicAdd(&counts[r4.x], 1);
    atomicAdd(&counts[r4.y], 1);
    atomicAdd(&counts[r4.z], 1);
    atomicAdd(&counts[r4.w], 1);
  }
}

// ---- scan: CH=64 per thread, int4 loads/stores, shfl wave-scan ----
__global__ void scan_kernel(const int* __restrict__ counts, int* __restrict__ offs) {
  __shared__ int wpre[17];
  const int t = threadIdx.x;            // 1024 threads
  const int lane = t & 63, w = t >> 6;  // 16 waves
  const int beg = t * 64;
  int4 c4[16];
  int s = 0;
  if (beg < NROWS) {
#pragma unroll
    for (int g = 0; g < 16; ++g) {
      int idx = beg + g * 4;
      if (idx < NROWS) {
        c4[g] = ((const int4*)counts)[idx >> 2];
        s += c4[g].x + c4[g].y + c4[g].z + c4[g].w;
      }
    }
  }
  int inc = s;
#pragma unroll
  for (int d = 1; d < 64; d <<= 1) {
    int u = __shfl_up(inc, d);
    if (lane >= d) inc += u;
  }
  if (lane == 63) wpre[w + 1] = inc;
  __syncthreads();
  if (t == 0) {
    wpre[0] = 0;
    for (int i = 1; i <= 16; ++i) wpre[i] += wpre[i - 1];
    offs[NROWS] = wpre[16];
  }
  __syncthreads();
  int run = wpre[w] + inc - s;
  if (beg < NROWS) {
#pragma unroll
    for (int g = 0; g < 16; ++g) {
      int idx = beg + g * 4;
      if (idx < NROWS) {
        int4 o;
        o.x = run; run += c4[g].x;
        o.y = run; run += c4[g].y;
        o.z = run; run += c4[g].z;
        o.w = run; run += c4[g].w;
        ((int4*)offs)[idx >> 2] = o;
      }
    }
  }
}

// ---- scatter: x4 vectorized reads, pack (val,col) int2, 8B random store ----
__global__ void scatter_kernel(const float* __restrict__ vals, const int* __restrict__ rows,
                               const int* __restrict__ cols, const int* __restrict__ offs,
                               int* __restrict__ cursor, int2* __restrict__ svc) {
  int e0 = (blockIdx.x * blockDim.x + threadIdx.x) * 4;
  if (e0 >= NEDGE) return;
  int4 r4 = *(const int4*)(rows + e0);
  int4 c4 = *(const int4*)(cols + e0);
  float4 v4 = *(const float4*)(vals + e0);
  int rr[4] = {r4.x, r4.y, r4.z, r4.w};
  int cc[4] = {c4.x, c4.y, c4.z, c4.w};
  float vv[4] = {v4.x, v4.y, v4.z, v4.w};
#pragma unroll
  for (int j = 0; j < 4; ++j) {
    int p = offs[rr[j]] + atomicAdd(&cursor[rr[j]], 1);
    int2 q;
    q.x = __float_as_int(vv[j]);
    q.y = cc[j];
    svc[p] = q;
  }
}

// ---- GEMM: BK=64, XOR-swizzled LDS, hq = int8(lrelu(xd@wb^T)/scale) ----
__global__ __launch_bounds__(256) void gemm_kernel(const u16* __restrict__ xd,
                                                   const u16* __restrict__ wb,
                                                   unsigned char* __restrict__ hq,
                                                   float* __restrict__ scaleg) {
  __shared__ __align__(16) u16 lAB[2 * 128 * 64];  // 32 KB
  __shared__ float wmax[2][128];
  __shared__ float rinv[128];
  u16* lA = lAB;
  u16* lB = lAB + 128 * 64;
  const int tid = threadIdx.x;
  const int lane = tid & 63;
  const int wid = tid >> 6;
  const int wm = wid >> 1, wn = wid & 1;
  const int bx = blockIdx.x;
  const int tm = bx >> 2;
  const int tn = bx & 3;
  const long rowBase = (long)tm * 128;

  f32x4 acc[4][4] = {};

  // staging: per call, one wave moves 8 rows x 128B; global col pre-swizzled
  const int sl8 = lane >> 3;                 // row within 8-row call
  const int scol = ((lane & 7) ^ sl8) * 8;   // swizzled col (u16 units)
  const int rsel = lane & 15, kgrp = (lane >> 4) * 8;

  for (int k0 = 0; k0 < 512; k0 += 64) {
    __syncthreads();
#pragma unroll
    for (int c = 0; c < 4; ++c) {
      int rbase = wid * 32 + c * 8;
      long gr = rowBase + rbase + sl8;
      if (gr > NROWS - 1) gr = NROWS - 1;
      gload_lds16(xd + gr * 512 + k0 + scol, lA + rbase * 64);
      gload_lds16(wb + ((long)tn * 128 + rbase + sl8) * 512 + k0 + scol, lB + rbase * 64);
    }
    __syncthreads();
    short8 a[4][2], b[4][2];
#pragma unroll
    for (int m = 0; m < 4; ++m) {
      int ar = wm * 64 + m * 16 + rsel;
      const u16* base = lA + ar * 64;
      int sw = (ar & 7) << 3;
      a[m][0] = *(const short8*)(base + (kgrp ^ sw));
      a[m][1] = *(const short8*)(base + ((32 + kgrp) ^ sw));
    }
#pragma unroll
    for (int n = 0; n < 4; ++n) {
      int br = wn * 64 + n * 16 + rsel;
      const u16* base = lB + br * 64;
      int sw = (br & 7) << 3;
      b[n][0] = *(const short8*)(base + (kgrp ^ sw));
      b[n][1] = *(const short8*)(base + ((32 + kgrp) ^ sw));
    }
#pragma unroll
    for (int kk = 0; kk < 2; ++kk)
#pragma unroll
      for (int m = 0; m < 4; ++m)
#pragma unroll
        for (int n = 0; n < 4; ++n)
          acc[m][n] = __builtin_amdgcn_mfma_f32_16x16x32_bf16(a[m][kk], b[n][kk], acc[m][n], 0, 0, 0);
  }

  // ---- epilogue: per-row max -> scale, int8 quantize, LDS byte-transpose ----
  const int crow = (lane >> 4) * 4;
  const int ccol = lane & 15;

  float pm[4][4];
#pragma unroll
  for (int m = 0; m < 4; ++m)
#pragma unroll
    for (int r2 = 0; r2 < 4; ++r2) {
      float mx = 0.f;
#pragma unroll
      for (int n = 0; n < 4; ++n) mx = fmaxf(mx, fabsf(lrelu(acc[m][n][r2])));
      pm[m][r2] = mx;
    }
#pragma unroll
  for (int d = 1; d < 16; d <<= 1)
#pragma unroll
    for (int m = 0; m < 4; ++m)
#pragma unroll
      for (int r2 = 0; r2 < 4; ++r2) pm[m][r2] = fmaxf(pm[m][r2], __shfl_xor(pm[m][r2], d));
  if ((lane & 15) == 0) {
#pragma unroll
    for (int m = 0; m < 4; ++m)
#pragma unroll
      for (int r2 = 0; r2 < 4; ++r2) wmax[wn][wm * 64 + m * 16 + crow + r2] = pm[m][r2];
  }
  __syncthreads();  // wmax ready AND all waves done reading lA/lB
  if (tid < 128) {
    float rm = fmaxf(wmax[0][tid], wmax[1][tid]);
    float s = rm > 0.f ? rm * (1.f / 127.f) : 1.f;
    rinv[tid] = rm > 0.f ? 127.f / rm : 0.f;
    long gr = rowBase + tid;
    if (gr < NROWS) scaleg[gr * 4 + tn] = s;
  }
  __syncthreads();

  unsigned char* lT = (unsigned char*)lAB;  // 128 x 128 int8 tile (16 KB of 32)
#pragma unroll
  for (int m = 0; m < 4; ++m) {
    int row0 = wm * 64 + m * 16 + crow;
    float ri0 = rinv[row0], ri1 = rinv[row0 + 1], ri2 = rinv[row0 + 2], ri3 = rinv[row0 + 3];
#pragma unroll
    for (int n = 0; n < 4; ++n) {
      int col = wn * 64 + n * 16 + ccol;
      float q0 = rintf(lrelu(acc[m][n][0]) * ri0);
      float q1 = rintf(lrelu(acc[m][n][1]) * ri1);
      float q2 = rintf(lrelu(acc[m][n][2]) * ri2);
      float q3 = rintf(lrelu(acc[m][n][3]) * ri3);
      int i0 = min(127, max(-127, (int)q0));
      int i1 = min(127, max(-127, (int)q1));
      int i2 = min(127, max(-127, (int)q2));
      int i3 = min(127, max(-127, (int)q3));
      unsigned pk = (i0 & 0xff) | ((i1 & 0xff) << 8) | ((i2 & 0xff) << 16) | ((i3 & 0xff) << 24);
#pragma unroll
      for (int r2 = 0; r2 < 4; ++r2) {
        int row = row0 + r2;
        lT[row * 128 + (col ^ ((row & 7) << 4))] = (unsigned char)(pk >> (8 * r2));
      }
    }
  }
  __syncthreads();
  {
    const int row = tid >> 1, seg = tid & 1;
    long gr = rowBase + row;
    if (gr < NROWS) {
      unsigned char* dst = hq + gr * 512 + tn * 128;
#pragma unroll
      for (int j = 0; j < 4; ++j) {
        int s = seg * 4 + j;
        int4 vv = *(const int4*)(lT + row * 128 + ((s ^ (row & 7)) << 4));
        *(int4*)(dst + s * 16) = vv;
      }
    }
  }
}

// ---- aggregate: wave per (row, feature-phase); 256-feature phases for L2 locality ----
__global__ __launch_bounds__(256) void aggregate_kernel(const unsigned char* __restrict__ hq,
                                                        const float* __restrict__ scaleg,
                                                        const int2* __restrict__ svc,
                                                        const int* __restrict__ offs,
                                                        float* __restrict__ out) {
  const int lane = threadIdx.x & 63;
  const int wid = threadIdx.x >> 6;
  const int p = blockIdx.x / 12500;            // feature phase 0/1 (slow-varying)
  const int r = (blockIdx.x % 12500) * 4 + wid;
  if (r >= NROWS) return;
  const int beg = offs[r], end = offs[r + 1];
  const int grp = p * 2 + (lane >> 5);         // 128-col scale block
  float a0 = 0.f, a1 = 0.f, a2 = 0.f, a3 = 0.f;
  const unsigned char* hp = hq + p * 256 + lane * 4;
  int2 cb[8], nb[8];
  const int ng = (end - beg) >> 3;
  if (ng > 0) {
#pragma unroll
    for (int k = 0; k < 8; ++k) cb[k] = svc[beg + k];
  }
  for (int g = 0; g < ng; ++g) {
    if (g + 1 < ng) {
#pragma unroll
      for (int k = 0; k < 8; ++k) nb[k] = svc[beg + (g + 1) * 8 + k];
    }
#pragma unroll
    for (int k = 0; k < 8; ++k) {
      float v = __int_as_float(cb[k].x);
      size_t c = (size_t)cb[k].y;
      float vs = v * scaleg[c * 4 + grp];
      unsigned q = *(const unsigned*)(hp + c * 512);
      a0 += vs * (float)(signed char)(q);
      a1 += vs * (float)(signed char)(q >> 8);
      a2 += vs * (float)(signed char)(q >> 16);
      a3 += vs * (float)(signed char)(q >> 24);
    }
    if (g + 1 < ng) {
#pragma unroll
      for (int k = 0; k < 8; ++k) cb[k] = nb[k];
    }
  }
  for (int e = beg + ng * 8; e < end; ++e) {
    int2 q2 = svc[e];
    float v = __int_as_float(q2.x);
    size_t c = (size_t)q2.y;
    float vs = v * scaleg[c * 4 + grp];
    unsigned q = *(const unsigned*)(hp + c * 512);
    a0 += vs * (float)(signed char)(q);
    a1 += vs * (float)(signed char)(q >> 8);
    a2 += vs * (float)(signed char)(q >> 16);
    a3 += vs * (float)(signed char)(q >> 24);
  }
  float4 o;
  o.x = lrelu(a0); o.y = lrelu(a1); o.z = lrelu(a2); o.w = lrelu(a3);
  *(float4*)(out + (size_t)r * NFEAT + p * 256 + lane * 4) = o;
}

extern "C" void kernel_launch(void* const* d_in, const int* in_sizes, int n_in,
                              void* d_out, int out_size, void* d_ws, size_t ws_size,
                              hipStream_t stream) {
  const float* x = (const float*)d_in[0];
  const float* W = (const float*)d_in[1];
  const float* mask = (const float*)d_in[2];
  const float* vals = (const float*)d_in[3];
  const int* rows = (const int*)d_in[4];
  const int* cols = (const int*)d_in[5];
  float* out = (float*)d_out;
  char* ws = (char*)d_ws;

  const size_t o_xd = 0;                       // 51,200,000 (bf16 x*mask)
  const size_t o_hq = o_xd + 51200000;         // 25,600,000 (int8 h)
  const size_t o_wb = o_hq + 25600000;         // 524,288
  const size_t o_scale = o_wb + 524288;        // 800,000 (f32 scale[row][4])
  const size_t o_counts = o_scale + 800000;    // 200,000
  const size_t o_cursor = o_counts + 200000;   // 200,000
  const size_t o_offs = o_cursor + 200000;     // 200,064
  const size_t o_svc = o_offs + 200064;        // 12,800,000 (int2 packed val/col)

  u16* xd = (u16*)(ws + o_xd);
  unsigned char* hq = (unsigned char*)(ws + o_hq);
  u16* wb = (u16*)(ws + o_wb);
  float* scaleg = (float*)(ws + o_scale);
  int* counts = (int*)(ws + o_counts);
  int* cursor = (int*)(ws + o_cursor);
  int* offs = (int*)(ws + o_offs);
  int2* svc = (int2*)(ws + o_svc);

  hipMemsetAsync(counts, 0, 400000, stream);  // counts + cursor

  prep_kernel<<<2048, 256, 0, stream>>>(x, mask, xd, W, wb, rows, counts);
  scan_kernel<<<1, 1024, 0, stream>>>(counts, offs);
  scatter_kernel<<<1563, 256, 0, stream>>>(vals, rows, cols, offs, cursor, svc);
  gemm_kernel<<<391 * 4, 256, 0, stream>>>(xd, wb, hq, scaleg);
  aggregate_kernel<<<25000, 256, 0, stream>>>(hq, scaleg, svc, offs, out);
}

// Round 6
// 405.802 us; speedup vs baseline: 1.4387x; 1.0441x over previous
//
#include <hip/hip_runtime.h>

#define NROWS 50000
#define NFEAT 512
#define NEDGE 1600000
#define SLOPE 0.01f

typedef unsigned short u16;
typedef __attribute__((ext_vector_type(8))) short short8;
typedef __attribute__((ext_vector_type(4))) float f32x4;
typedef __attribute__((ext_vector_type(8))) unsigned short u16x8;

__device__ __forceinline__ u16 f2bf(float f) {
  unsigned u = __float_as_uint(f);
  u += 0x7fffu + ((u >> 16) & 1u);
  return (u16)(u >> 16);
}
__device__ __forceinline__ float lrelu(float v) { return v >= 0.f ? v : SLOPE * v; }

__device__ __forceinline__ void gload_lds16(const u16* g, u16* l) {
  __builtin_amdgcn_global_load_lds((const __attribute__((address_space(1))) void*)g,
                                   (__attribute__((address_space(3))) void*)l, 16, 0, 0);
}

// ---- fused prep: xd = bf16(x*mask), wb = bf16(W), counts = row histogram ----
__global__ void prep_kernel(const float* __restrict__ x, const float* __restrict__ m,
                            u16* __restrict__ xd, const float* __restrict__ w,
                            u16* __restrict__ wb, const int* __restrict__ rows,
                            int* __restrict__ counts) {
  const int stride = gridDim.x * blockDim.x;
  const int tid0 = blockIdx.x * blockDim.x + threadIdx.x;
  for (int i = tid0; i < (NROWS * NFEAT) / 8; i += stride) {
    size_t b = (size_t)i * 2;
    float4 a0 = ((const float4*)x)[b], a1 = ((const float4*)x)[b + 1];
    float4 m0 = ((const float4*)m)[b], m1 = ((const float4*)m)[b + 1];
    u16x8 o;
    o[0] = f2bf(a0.x * m0.x); o[1] = f2bf(a0.y * m0.y);
    o[2] = f2bf(a0.z * m0.z); o[3] = f2bf(a0.w * m0.w);
    o[4] = f2bf(a1.x * m1.x); o[5] = f2bf(a1.y * m1.y);
    o[6] = f2bf(a1.z * m1.z); o[7] = f2bf(a1.w * m1.w);
    *(u16x8*)(xd + (size_t)i * 8) = o;
  }
  for (int i = tid0; i < (NFEAT * NFEAT) / 8; i += stride) {
    size_t b = (size_t)i * 2;
    float4 a0 = ((const float4*)w)[b], a1 = ((const float4*)w)[b + 1];
    u16x8 o;
    o[0] = f2bf(a0.x); o[1] = f2bf(a0.y); o[2] = f2bf(a0.z); o[3] = f2bf(a0.w);
    o[4] = f2bf(a1.x); o[5] = f2bf(a1.y); o[6] = f2bf(a1.z); o[7] = f2bf(a1.w);
    *(u16x8*)(wb + (size_t)i * 8) = o;
  }
  for (int i = tid0; i < NEDGE / 4; i += stride) {
    int4 r4 = ((const int4*)rows)[i];
    atomicAdd(&counts[r4.x], 1);
    atomicAdd(&counts[r4.y], 1);
    atomicAdd(&counts[r4.z], 1);
    atomicAdd(&counts[r4.w], 1);
  }
}

// ---- scan: CH=64 per thread, int4 loads/stores, shfl wave-scan ----
__global__ void scan_kernel(const int* __restrict__ counts, int* __restrict__ offs) {
  __shared__ int wpre[17];
  const int t = threadIdx.x;            // 1024 threads
  const int lane = t & 63, w = t >> 6;  // 16 waves
  const int beg = t * 64;
  int4 c4[16];
  int s = 0;
  if (beg < NROWS) {
#pragma unroll
    for (int g = 0; g < 16; ++g) {
      int idx = beg + g * 4;
      if (idx < NROWS) {
        c4[g] = ((const int4*)counts)[idx >> 2];
        s += c4[g].x + c4[g].y + c4[g].z + c4[g].w;
      }
    }
  }
  int inc = s;
#pragma unroll
  for (int d = 1; d < 64; d <<= 1) {
    int u = __shfl_up(inc, d);
    if (lane >= d) inc += u;
  }
  if (lane == 63) wpre[w + 1] = inc;
  __syncthreads();
  if (t == 0) {
    wpre[0] = 0;
    for (int i = 1; i <= 16; ++i) wpre[i] += wpre[i - 1];
    offs[NROWS] = wpre[16];
  }
  __syncthreads();
  int run = wpre[w] + inc - s;
  if (beg < NROWS) {
#pragma unroll
    for (int g = 0; g < 16; ++g) {
      int idx = beg + g * 4;
      if (idx < NROWS) {
        int4 o;
        o.x = run; run += c4[g].x;
        o.y = run; run += c4[g].y;
        o.z = run; run += c4[g].z;
        o.w = run; run += c4[g].w;
        ((int4*)offs)[idx >> 2] = o;
      }
    }
  }
}

// ---- scatter: pack (col<<16 | bf16(val)) into u32, 4B random store ----
__global__ void scatter_kernel(const float* __restrict__ vals, const int* __restrict__ rows,
                               const int* __restrict__ cols, const int* __restrict__ offs,
                               int* __restrict__ cursor, unsigned* __restrict__ svc) {
  int e0 = (blockIdx.x * blockDim.x + threadIdx.x) * 4;
  if (e0 >= NEDGE) return;
  int4 r4 = *(const int4*)(rows + e0);
  int4 c4 = *(const int4*)(cols + e0);
  float4 v4 = *(const float4*)(vals + e0);
  int rr[4] = {r4.x, r4.y, r4.z, r4.w};
  int cc[4] = {c4.x, c4.y, c4.z, c4.w};
  float vv[4] = {v4.x, v4.y, v4.z, v4.w};
#pragma unroll
  for (int j = 0; j < 4; ++j) {
    int p = offs[rr[j]] + atomicAdd(&cursor[rr[j]], 1);
    svc[p] = ((unsigned)cc[j] << 16) | (unsigned)f2bf(vv[j]);
  }
}

// ---- GEMM: BK=64, XOR-swizzled LDS, XCD-swizzled blocks, int8 output ----
__global__ __launch_bounds__(256) void gemm_kernel(const u16* __restrict__ xd,
                                                   const u16* __restrict__ wb,
                                                   unsigned char* __restrict__ hq,
                                                   float* __restrict__ scaleg) {
  __shared__ __align__(16) u16 lAB[2 * 128 * 64];  // 32 KB
  __shared__ float wmax[2][128];
  __shared__ float rinv[128];
  u16* lA = lAB;
  u16* lB = lAB + 128 * 64;
  const int tid = threadIdx.x;
  const int lane = tid & 63;
  const int wid = tid >> 6;
  const int wm = wid >> 1, wn = wid & 1;
  // bijective XCD swizzle: nwg = 1564 = 4*196 + 4*195 (q=195, r=4)
  const int bx0 = blockIdx.x;
  const int xcd = bx0 & 7, idx = bx0 >> 3;
  const int wg = (xcd < 4 ? xcd * 196 : 784 + (xcd - 4) * 195) + idx;
  const int tm = wg >> 2;
  const int tn = wg & 3;
  const long rowBase = (long)tm * 128;

  f32x4 acc[4][4] = {};

  const int sl8 = lane >> 3;                 // row within 8-row staging call
  const int scol = ((lane & 7) ^ sl8) * 8;   // pre-swizzled global col (u16 units)
  const int rsel = lane & 15, kgrp = (lane >> 4) * 8;

  for (int k0 = 0; k0 < 512; k0 += 64) {
    __syncthreads();
#pragma unroll
    for (int c = 0; c < 4; ++c) {
      int rbase = wid * 32 + c * 8;
      long gr = rowBase + rbase + sl8;
      if (gr > NROWS - 1) gr = NROWS - 1;
      gload_lds16(xd + gr * 512 + k0 + scol, lA + rbase * 64);
      gload_lds16(wb + ((long)tn * 128 + rbase + sl8) * 512 + k0 + scol, lB + rbase * 64);
    }
    __syncthreads();
    short8 a[4][2], b[4][2];
#pragma unroll
    for (int m = 0; m < 4; ++m) {
      int ar = wm * 64 + m * 16 + rsel;
      const u16* base = lA + ar * 64;
      int sw = (ar & 7) << 3;
      a[m][0] = *(const short8*)(base + (kgrp ^ sw));
      a[m][1] = *(const short8*)(base + ((32 + kgrp) ^ sw));
    }
#pragma unroll
    for (int n = 0; n < 4; ++n) {
      int br = wn * 64 + n * 16 + rsel;
      const u16* base = lB + br * 64;
      int sw = (br & 7) << 3;
      b[n][0] = *(const short8*)(base + (kgrp ^ sw));
      b[n][1] = *(const short8*)(base + ((32 + kgrp) ^ sw));
    }
#pragma unroll
    for (int kk = 0; kk < 2; ++kk)
#pragma unroll
      for (int m = 0; m < 4; ++m)
#pragma unroll
        for (int n = 0; n < 4; ++n)
          acc[m][n] = __builtin_amdgcn_mfma_f32_16x16x32_bf16(a[m][kk], b[n][kk], acc[m][n], 0, 0, 0);
  }

  // ---- epilogue: per-row max -> scale, int8 quantize, LDS byte-transpose ----
  const int crow = (lane >> 4) * 4;
  const int ccol = lane & 15;

  float pm[4][4];
#pragma unroll
  for (int m = 0; m < 4; ++m)
#pragma unroll
    for (int r2 = 0; r2 < 4; ++r2) {
      float mx = 0.f;
#pragma unroll
      for (int n = 0; n < 4; ++n) mx = fmaxf(mx, fabsf(lrelu(acc[m][n][r2])));
      pm[m][r2] = mx;
    }
#pragma unroll
  for (int d = 1; d < 16; d <<= 1)
#pragma unroll
    for (int m = 0; m < 4; ++m)
#pragma unroll
      for (int r2 = 0; r2 < 4; ++r2) pm[m][r2] = fmaxf(pm[m][r2], __shfl_xor(pm[m][r2], d));
  if ((lane & 15) == 0) {
#pragma unroll
    for (int m = 0; m < 4; ++m)
#pragma unroll
      for (int r2 = 0; r2 < 4; ++r2) wmax[wn][wm * 64 + m * 16 + crow + r2] = pm[m][r2];
  }
  __syncthreads();  // wmax ready AND all waves done reading lA/lB
  if (tid < 128) {
    float rm = fmaxf(wmax[0][tid], wmax[1][tid]);
    float s = rm > 0.f ? rm * (1.f / 127.f) : 1.f;
    rinv[tid] = rm > 0.f ? 127.f / rm : 0.f;
    long gr = rowBase + tid;
    if (gr < NROWS) scaleg[gr * 4 + tn] = s;
  }
  __syncthreads();

  unsigned char* lT = (unsigned char*)lAB;  // 128 x 128 int8 tile
#pragma unroll
  for (int m = 0; m < 4; ++m) {
    int row0 = wm * 64 + m * 16 + crow;
    float ri0 = rinv[row0], ri1 = rinv[row0 + 1], ri2 = rinv[row0 + 2], ri3 = rinv[row0 + 3];
#pragma unroll
    for (int n = 0; n < 4; ++n) {
      int col = wn * 64 + n * 16 + ccol;
      float q0 = rintf(lrelu(acc[m][n][0]) * ri0);
      float q1 = rintf(lrelu(acc[m][n][1]) * ri1);
      float q2 = rintf(lrelu(acc[m][n][2]) * ri2);
      float q3 = rintf(lrelu(acc[m][n][3]) * ri3);
      int i0 = min(127, max(-127, (int)q0));
      int i1 = min(127, max(-127, (int)q1));
      int i2 = min(127, max(-127, (int)q2));
      int i3 = min(127, max(-127, (int)q3));
      unsigned pk = (i0 & 0xff) | ((i1 & 0xff) << 8) | ((i2 & 0xff) << 16) | ((i3 & 0xff) << 24);
#pragma unroll
      for (int r2 = 0; r2 < 4; ++r2) {
        int row = row0 + r2;
        lT[row * 128 + (col ^ ((row & 7) << 4))] = (unsigned char)(pk >> (8 * r2));
      }
    }
  }
  __syncthreads();
  {
    const int row = tid >> 1, seg = tid & 1;
    long gr = rowBase + row;
    if (gr < NROWS) {
      unsigned char* dst = hq + gr * 512 + tn * 128;
#pragma unroll
      for (int j = 0; j < 4; ++j) {
        int s = seg * 4 + j;
        int4 vv = *(const int4*)(lT + row * 128 + ((s ^ (row & 7)) << 4));
        *(int4*)(dst + s * 16) = vv;
      }
    }
  }
}

// ---- aggregate: one WAVE per row, int8 gathers 8B/lane, packed 4B edges ----
__global__ __launch_bounds__(256) void aggregate_kernel(const unsigned char* __restrict__ hq,
                                                        const float* __restrict__ scaleg,
                                                        const unsigned* __restrict__ svc,
                                                        const int* __restrict__ offs,
                                                        float* __restrict__ out) {
  const int lane = threadIdx.x & 63;
  const int wid = threadIdx.x >> 6;
  const int r = blockIdx.x * 4 + wid;
  if (r >= NROWS) return;
  const int beg = offs[r], end = offs[r + 1];
  const int grp = lane >> 4;
  float a[8] = {};
  const unsigned char* hp = hq + lane * 8;
  unsigned cb[8], nb[8];
  const int ng = (end - beg) >> 3;
  if (ng > 0) {
#pragma unroll
    for (int k = 0; k < 8; ++k) cb[k] = svc[beg + k];
  }
  for (int g = 0; g < ng; ++g) {
    if (g + 1 < ng) {
#pragma unroll
      for (int k = 0; k < 8; ++k) nb[k] = svc[beg + (g + 1) * 8 + k];
    }
#pragma unroll
    for (int k = 0; k < 8; ++k) {
      float v = __uint_as_float(cb[k] << 16);   // bf16 val
      size_t c = (size_t)(cb[k] >> 16);          // col
      float vs = v * scaleg[c * 4 + grp];
      uint2 q = *(const uint2*)(hp + c * 512);
      a[0] += vs * (float)(signed char)(q.x);
      a[1] += vs * (float)(signed char)(q.x >> 8);
      a[2] += vs * (float)(signed char)(q.x >> 16);
      a[3] += vs * (float)(signed char)(q.x >> 24);
      a[4] += vs * (float)(signed char)(q.y);
      a[5] += vs * (float)(signed char)(q.y >> 8);
      a[6] += vs * (float)(signed char)(q.y >> 16);
      a[7] += vs * (float)(signed char)(q.y >> 24);
    }
    if (g + 1 < ng) {
#pragma unroll
      for (int k = 0; k < 8; ++k) cb[k] = nb[k];
    }
  }
  for (int e = beg + ng * 8; e < end; ++e) {
    unsigned q2 = svc[e];
    float v = __uint_as_float(q2 << 16);
    size_t c = (size_t)(q2 >> 16);
    float vs = v * scaleg[c * 4 + grp];
    uint2 q = *(const uint2*)(hp + c * 512);
    a[0] += vs * (float)(signed char)(q.x);
    a[1] += vs * (float)(signed char)(q.x >> 8);
    a[2] += vs * (float)(signed char)(q.x >> 16);
    a[3] += vs * (float)(signed char)(q.x >> 24);
    a[4] += vs * (float)(signed char)(q.y);
    a[5] += vs * (float)(signed char)(q.y >> 8);
    a[6] += vs * (float)(signed char)(q.y >> 16);
    a[7] += vs * (float)(signed char)(q.y >> 24);
  }
  float* op = out + (size_t)r * NFEAT + lane * 8;
  float4 o0, o1;
  o0.x = lrelu(a[0]); o0.y = lrelu(a[1]); o0.z = lrelu(a[2]); o0.w = lrelu(a[3]);
  o1.x = lrelu(a[4]); o1.y = lrelu(a[5]); o1.z = lrelu(a[6]); o1.w = lrelu(a[7]);
  *(float4*)op = o0;
  *(float4*)(op + 4) = o1;
}

extern "C" void kernel_launch(void* const* d_in, const int* in_sizes, int n_in,
                              void* d_out, int out_size, void* d_ws, size_t ws_size,
                              hipStream_t stream) {
  const float* x = (const float*)d_in[0];
  const float* W = (const float*)d_in[1];
  const float* mask = (const float*)d_in[2];
  const float* vals = (const float*)d_in[3];
  const int* rows = (const int*)d_in[4];
  const int* cols = (const int*)d_in[5];
  float* out = (float*)d_out;
  char* ws = (char*)d_ws;

  const size_t o_xd = 0;                       // 51,200,000 (bf16 x*mask)
  const size_t o_hq = o_xd + 51200000;         // 25,600,000 (int8 h)
  const size_t o_wb = o_hq + 25600000;         // 524,288
  const size_t o_scale = o_wb + 524288;        // 800,000 (f32 scale[row][4])
  const size_t o_counts = o_scale + 800000;    // 200,000
  const size_t o_cursor = o_counts + 200000;   // 200,000
  const size_t o_offs = o_cursor + 200000;     // 200,064
  const size_t o_svc = o_offs + 200064;        // 6,400,000 (u32 packed col|bf16val)

  u16* xd = (u16*)(ws + o_xd);
  unsigned char* hq = (unsigned char*)(ws + o_hq);
  u16* wb = (u16*)(ws + o_wb);
  float* scaleg = (float*)(ws + o_scale);
  int* counts = (int*)(ws + o_counts);
  int* cursor = (int*)(ws + o_cursor);
  int* offs = (int*)(ws + o_offs);
  unsigned* svc = (unsigned*)(ws + o_svc);

  hipMemsetAsync(counts, 0, 400000, stream);  // counts + cursor

  prep_kernel<<<2048, 256, 0, stream>>>(x, mask, xd, W, wb, rows, counts);
  scan_kernel<<<1, 1024, 0, stream>>>(counts, offs);
  scatter_kernel<<<1563, 256, 0, stream>>>(vals, rows, cols, offs, cursor, svc);
  gemm_kernel<<<391 * 4, 256, 0, stream>>>(xd, wb, hq, scaleg);
  aggregate_kernel<<<12500, 256, 0, stream>>>(hq, scaleg, svc, offs, out);
}

// Round 8
// 404.920 us; speedup vs baseline: 1.4419x; 1.0022x over previous
//
#include <hip/hip_runtime.h>

#define NROWS 50000
#define NFEAT 512
#define NEDGE 1600000
#define SLOPE 0.01f

typedef unsigned short u16;
typedef __attribute__((ext_vector_type(8))) short short8;
typedef __attribute__((ext_vector_type(4))) float f32x4;
typedef __attribute__((ext_vector_type(4))) int i32x4;
typedef __attribute__((ext_vector_type(2))) unsigned uintx2;
typedef __attribute__((ext_vector_type(8))) unsigned short u16x8;

__device__ __forceinline__ u16 f2bf(float f) {
  unsigned u = __float_as_uint(f);
  u += 0x7fffu + ((u >> 16) & 1u);
  return (u16)(u >> 16);
}
__device__ __forceinline__ float lrelu(float v) { return v >= 0.f ? v : SLOPE * v; }

__device__ __forceinline__ void gload_lds16(const u16* g, u16* l) {
  __builtin_amdgcn_global_load_lds((const __attribute__((address_space(1))) void*)g,
                                   (__attribute__((address_space(3))) void*)l, 16, 0, 0);
}

// ---- fused prep: xd = bf16(x*mask), wb = bf16(W), counts = row histogram ----
__global__ void prep_kernel(const float* __restrict__ x, const float* __restrict__ m,
                            u16* __restrict__ xd, const float* __restrict__ w,
                            u16* __restrict__ wb, const int* __restrict__ rows,
                            int* __restrict__ counts) {
  const int stride = gridDim.x * blockDim.x;
  const int tid0 = blockIdx.x * blockDim.x + threadIdx.x;
  for (int i = tid0; i < (NROWS * NFEAT) / 8; i += stride) {
    size_t b = (size_t)i * 2;
    f32x4 a0 = __builtin_nontemporal_load(&((const f32x4*)x)[b]);
    f32x4 a1 = __builtin_nontemporal_load(&((const f32x4*)x)[b + 1]);
    f32x4 m0 = __builtin_nontemporal_load(&((const f32x4*)m)[b]);
    f32x4 m1 = __builtin_nontemporal_load(&((const f32x4*)m)[b + 1]);
    u16x8 o;
    o[0] = f2bf(a0[0] * m0[0]); o[1] = f2bf(a0[1] * m0[1]);
    o[2] = f2bf(a0[2] * m0[2]); o[3] = f2bf(a0[3] * m0[3]);
    o[4] = f2bf(a1[0] * m1[0]); o[5] = f2bf(a1[1] * m1[1]);
    o[6] = f2bf(a1[2] * m1[2]); o[7] = f2bf(a1[3] * m1[3]);
    *(u16x8*)(xd + (size_t)i * 8) = o;
  }
  for (int i = tid0; i < (NFEAT * NFEAT) / 8; i += stride) {
    size_t b = (size_t)i * 2;
    f32x4 a0 = __builtin_nontemporal_load(&((const f32x4*)w)[b]);
    f32x4 a1 = __builtin_nontemporal_load(&((const f32x4*)w)[b + 1]);
    u16x8 o;
    o[0] = f2bf(a0[0]); o[1] = f2bf(a0[1]); o[2] = f2bf(a0[2]); o[3] = f2bf(a0[3]);
    o[4] = f2bf(a1[0]); o[5] = f2bf(a1[1]); o[6] = f2bf(a1[2]); o[7] = f2bf(a1[3]);
    *(u16x8*)(wb + (size_t)i * 8) = o;
  }
  for (int i = tid0; i < NEDGE / 4; i += stride) {
    i32x4 r4 = __builtin_nontemporal_load(&((const i32x4*)rows)[i]);
    atomicAdd(&counts[r4[0]], 1);
    atomicAdd(&counts[r4[1]], 1);
    atomicAdd(&counts[r4[2]], 1);
    atomicAdd(&counts[r4[3]], 1);
  }
}

// ---- scan: CH=64 per thread, int4 loads/stores, shfl wave-scan ----
__global__ void scan_kernel(const int* __restrict__ counts, int* __restrict__ offs) {
  __shared__ int wpre[17];
  const int t = threadIdx.x;            // 1024 threads
  const int lane = t & 63, w = t >> 6;  // 16 waves
  const int beg = t * 64;
  i32x4 c4[16];
  int s = 0;
  if (beg < NROWS) {
#pragma unroll
    for (int g = 0; g < 16; ++g) {
      int idx = beg + g * 4;
      if (idx < NROWS) {
        c4[g] = ((const i32x4*)counts)[idx >> 2];
        s += c4[g][0] + c4[g][1] + c4[g][2] + c4[g][3];
      }
    }
  }
  int inc = s;
#pragma unroll
  for (int d = 1; d < 64; d <<= 1) {
    int u = __shfl_up(inc, d);
    if (lane >= d) inc += u;
  }
  if (lane == 63) wpre[w + 1] = inc;
  __syncthreads();
  if (t == 0) {
    wpre[0] = 0;
    for (int i = 1; i <= 16; ++i) wpre[i] += wpre[i - 1];
    offs[NROWS] = wpre[16];
  }
  __syncthreads();
  int run = wpre[w] + inc - s;
  if (beg < NROWS) {
#pragma unroll
    for (int g = 0; g < 16; ++g) {
      int idx = beg + g * 4;
      if (idx < NROWS) {
        i32x4 o;
        o[0] = run; run += c4[g][0];
        o[1] = run; run += c4[g][1];
        o[2] = run; run += c4[g][2];
        o[3] = run; run += c4[g][3];
        ((i32x4*)offs)[idx >> 2] = o;
      }
    }
  }
}

// ---- scatter: pack (col<<16 | bf16(val)) into u32, 4B random store ----
__global__ void scatter_kernel(const float* __restrict__ vals, const int* __restrict__ rows,
                               const int* __restrict__ cols, const int* __restrict__ offs,
                               int* __restrict__ cursor, unsigned* __restrict__ svc) {
  int e0 = (blockIdx.x * blockDim.x + threadIdx.x) * 4;
  if (e0 >= NEDGE) return;
  i32x4 r4 = __builtin_nontemporal_load((const i32x4*)(rows + e0));
  i32x4 c4 = __builtin_nontemporal_load((const i32x4*)(cols + e0));
  f32x4 v4 = __builtin_nontemporal_load((const f32x4*)(vals + e0));
#pragma unroll
  for (int j = 0; j < 4; ++j) {
    int p = offs[r4[j]] + atomicAdd(&cursor[r4[j]], 1);
    svc[p] = ((unsigned)c4[j] << 16) | (unsigned)f2bf(v4[j]);
  }
}

// ---- GEMM: BK=64, XOR-swizzled LDS, XCD-swizzled blocks, int8 output ----
__global__ __launch_bounds__(256) void gemm_kernel(const u16* __restrict__ xd,
                                                   const u16* __restrict__ wb,
                                                   unsigned char* __restrict__ hq,
                                                   float* __restrict__ scaleg) {
  __shared__ __align__(16) u16 lAB[2 * 128 * 64];  // 32 KB
  __shared__ float wmax[2][128];
  __shared__ float rinv[128];
  u16* lA = lAB;
  u16* lB = lAB + 128 * 64;
  const int tid = threadIdx.x;
  const int lane = tid & 63;
  const int wid = tid >> 6;
  const int wm = wid >> 1, wn = wid & 1;
  // bijective XCD swizzle: nwg = 1564 = 4*196 + 4*195 (q=195, r=4)
  const int bx0 = blockIdx.x;
  const int xcd = bx0 & 7, idx = bx0 >> 3;
  const int wg = (xcd < 4 ? xcd * 196 : 784 + (xcd - 4) * 195) + idx;
  const int tm = wg >> 2;
  const int tn = wg & 3;
  const long rowBase = (long)tm * 128;

  f32x4 acc[4][4] = {};

  const int sl8 = lane >> 3;                 // row within 8-row staging call
  const int scol = ((lane & 7) ^ sl8) * 8;   // pre-swizzled global col (u16 units)
  const int rsel = lane & 15, kgrp = (lane >> 4) * 8;

  for (int k0 = 0; k0 < 512; k0 += 64) {
    __syncthreads();
#pragma unroll
    for (int c = 0; c < 4; ++c) {
      int rbase = wid * 32 + c * 8;
      long gr = rowBase + rbase + sl8;
      if (gr > NROWS - 1) gr = NROWS - 1;
      gload_lds16(xd + gr * 512 + k0 + scol, lA + rbase * 64);
      gload_lds16(wb + ((long)tn * 128 + rbase + sl8) * 512 + k0 + scol, lB + rbase * 64);
    }
    __syncthreads();
    short8 a[4][2], b[4][2];
#pragma unroll
    for (int m = 0; m < 4; ++m) {
      int ar = wm * 64 + m * 16 + rsel;
      const u16* base = lA + ar * 64;
      int sw = (ar & 7) << 3;
      a[m][0] = *(const short8*)(base + (kgrp ^ sw));
      a[m][1] = *(const short8*)(base + ((32 + kgrp) ^ sw));
    }
#pragma unroll
    for (int n = 0; n < 4; ++n) {
      int br = wn * 64 + n * 16 + rsel;
      const u16* base = lB + br * 64;
      int sw = (br & 7) << 3;
      b[n][0] = *(const short8*)(base + (kgrp ^ sw));
      b[n][1] = *(const short8*)(base + ((32 + kgrp) ^ sw));
    }
#pragma unroll
    for (int kk = 0; kk < 2; ++kk)
#pragma unroll
      for (int m = 0; m < 4; ++m)
#pragma unroll
        for (int n = 0; n < 4; ++n)
          acc[m][n] = __builtin_amdgcn_mfma_f32_16x16x32_bf16(a[m][kk], b[n][kk], acc[m][n], 0, 0, 0);
  }

  // ---- epilogue: per-row max -> scale, int8 quantize, LDS byte-transpose ----
  const int crow = (lane >> 4) * 4;
  const int ccol = lane & 15;

  float pm[4][4];
#pragma unroll
  for (int m = 0; m < 4; ++m)
#pragma unroll
    for (int r2 = 0; r2 < 4; ++r2) {
      float mx = 0.f;
#pragma unroll
      for (int n = 0; n < 4; ++n) mx = fmaxf(mx, fabsf(lrelu(acc[m][n][r2])));
      pm[m][r2] = mx;
    }
#pragma unroll
  for (int d = 1; d < 16; d <<= 1)
#pragma unroll
    for (int m = 0; m < 4; ++m)
#pragma unroll
      for (int r2 = 0; r2 < 4; ++r2) pm[m][r2] = fmaxf(pm[m][r2], __shfl_xor(pm[m][r2], d));
  if ((lane & 15) == 0) {
#pragma unroll
    for (int m = 0; m < 4; ++m)
#pragma unroll
      for (int r2 = 0; r2 < 4; ++r2) wmax[wn][wm * 64 + m * 16 + crow + r2] = pm[m][r2];
  }
  __syncthreads();  // wmax ready AND all waves done reading lA/lB
  if (tid < 128) {
    float rm = fmaxf(wmax[0][tid], wmax[1][tid]);
    float s = rm > 0.f ? rm * (1.f / 127.f) : 1.f;
    rinv[tid] = rm > 0.f ? 127.f / rm : 0.f;
    long gr = rowBase + tid;
    if (gr < NROWS) scaleg[gr * 4 + tn] = s;
  }
  __syncthreads();

  unsigned char* lT = (unsigned char*)lAB;  // 128 x 128 int8 tile
#pragma unroll
  for (int m = 0; m < 4; ++m) {
    int row0 = wm * 64 + m * 16 + crow;
    float ri0 = rinv[row0], ri1 = rinv[row0 + 1], ri2 = rinv[row0 + 2], ri3 = rinv[row0 + 3];
#pragma unroll
    for (int n = 0; n < 4; ++n) {
      int col = wn * 64 + n * 16 + ccol;
      float q0 = rintf(lrelu(acc[m][n][0]) * ri0);
      float q1 = rintf(lrelu(acc[m][n][1]) * ri1);
      float q2 = rintf(lrelu(acc[m][n][2]) * ri2);
      float q3 = rintf(lrelu(acc[m][n][3]) * ri3);
      int i0 = min(127, max(-127, (int)q0));
      int i1 = min(127, max(-127, (int)q1));
      int i2 = min(127, max(-127, (int)q2));
      int i3 = min(127, max(-127, (int)q3));
      unsigned pk = (i0 & 0xff) | ((i1 & 0xff) << 8) | ((i2 & 0xff) << 16) | ((i3 & 0xff) << 24);
#pragma unroll
      for (int r2 = 0; r2 < 4; ++r2) {
        int row = row0 + r2;
        lT[row * 128 + (col ^ ((row & 7) << 4))] = (unsigned char)(pk >> (8 * r2));
      }
    }
  }
  __syncthreads();
  {
    const int row = tid >> 1, seg = tid & 1;
    long gr = rowBase + row;
    if (gr < NROWS) {
      unsigned char* dst = hq + gr * 512 + tn * 128;
#pragma unroll
      for (int j = 0; j < 4; ++j) {
        int s = seg * 4 + j;
        i32x4 vv = *(const i32x4*)(lT + row * 128 + ((s ^ (row & 7)) << 4));
        *(i32x4*)(dst + s * 16) = vv;
      }
    }
  }
}

// ---- aggregate: one WAVE per row, int8 gathers 8B/lane, nt out stores ----
__global__ __launch_bounds__(256) void aggregate_kernel(const unsigned char* __restrict__ hq,
                                                        const float* __restrict__ scaleg,
                                                        const unsigned* __restrict__ svc,
                                                        const int* __restrict__ offs,
                                                        float* __restrict__ out) {
  const int lane = threadIdx.x & 63;
  const int wid = threadIdx.x >> 6;
  const int r = blockIdx.x * 4 + wid;
  if (r >= NROWS) return;
  const int beg = offs[r], end = offs[r + 1];
  const int grp = lane >> 4;
  float a[8] = {};
  const unsigned char* hp = hq + lane * 8;
  unsigned cb[8], nb[8];
  const int ng = (end - beg) >> 3;
  if (ng > 0) {
#pragma unroll
    for (int k = 0; k < 8; ++k) cb[k] = __builtin_nontemporal_load(&svc[beg + k]);
  }
  for (int g = 0; g < ng; ++g) {
    if (g + 1 < ng) {
#pragma unroll
      for (int k = 0; k < 8; ++k) nb[k] = __builtin_nontemporal_load(&svc[beg + (g + 1) * 8 + k]);
    }
#pragma unroll
    for (int k = 0; k < 8; ++k) {
      float v = __uint_as_float(cb[k] << 16);   // bf16 val
      size_t c = (size_t)(cb[k] >> 16);          // col
      float vs = v * scaleg[c * 4 + grp];
      uintx2 q = *(const uintx2*)(hp + c * 512);
      a[0] += vs * (float)(signed char)(q[0]);
      a[1] += vs * (float)(signed char)(q[0] >> 8);
      a[2] += vs * (float)(signed char)(q[0] >> 16);
      a[3] += vs * (float)(signed char)(q[0] >> 24);
      a[4] += vs * (float)(signed char)(q[1]);
      a[5] += vs * (float)(signed char)(q[1] >> 8);
      a[6] += vs * (float)(signed char)(q[1] >> 16);
      a[7] += vs * (float)(signed char)(q[1] >> 24);
    }
    if (g + 1 < ng) {
#pragma unroll
      for (int k = 0; k < 8; ++k) cb[k] = nb[k];
    }
  }
  for (int e = beg + ng * 8; e < end; ++e) {
    unsigned q2 = __builtin_nontemporal_load(&svc[e]);
    float v = __uint_as_float(q2 << 16);
    size_t c = (size_t)(q2 >> 16);
    float vs = v * scaleg[c * 4 + grp];
    uintx2 q = *(const uintx2*)(hp + c * 512);
    a[0] += vs * (float)(signed char)(q[0]);
    a[1] += vs * (float)(signed char)(q[0] >> 8);
    a[2] += vs * (float)(signed char)(q[0] >> 16);
    a[3] += vs * (float)(signed char)(q[0] >> 24);
    a[4] += vs * (float)(signed char)(q[1]);
    a[5] += vs * (float)(signed char)(q[1] >> 8);
    a[6] += vs * (float)(signed char)(q[1] >> 16);
    a[7] += vs * (float)(signed char)(q[1] >> 24);
  }
  float* op = out + (size_t)r * NFEAT + lane * 8;
  f32x4 o0, o1;
  o0[0] = lrelu(a[0]); o0[1] = lrelu(a[1]); o0[2] = lrelu(a[2]); o0[3] = lrelu(a[3]);
  o1[0] = lrelu(a[4]); o1[1] = lrelu(a[5]); o1[2] = lrelu(a[6]); o1[3] = lrelu(a[7]);
  __builtin_nontemporal_store(o0, (f32x4*)op);
  __builtin_nontemporal_store(o1, (f32x4*)(op + 4));
}

extern "C" void kernel_launch(void* const* d_in, const int* in_sizes, int n_in,
                              void* d_out, int out_size, void* d_ws, size_t ws_size,
                              hipStream_t stream) {
  const float* x = (const float*)d_in[0];
  const float* W = (const float*)d_in[1];
  const float* mask = (const float*)d_in[2];
  const float* vals = (const float*)d_in[3];
  const int* rows = (const int*)d_in[4];
  const int* cols = (const int*)d_in[5];
  float* out = (float*)d_out;
  char* ws = (char*)d_ws;

  const size_t o_xd = 0;                       // 51,200,000 (bf16 x*mask)
  const size_t o_hq = o_xd + 51200000;         // 25,600,000 (int8 h)
  const size_t o_wb = o_hq + 25600000;         // 524,288
  const size_t o_scale = o_wb + 524288;        // 800,000 (f32 scale[row][4])
  const size_t o_counts = o_scale + 800000;    // 200,000
  const size_t o_cursor = o_counts + 200000;   // 200,000
  const size_t o_offs = o_cursor + 200000;     // 200,064
  const size_t o_svc = o_offs + 200064;        // 6,400,000 (u32 packed col|bf16val)

  u16* xd = (u16*)(ws + o_xd);
  unsigned char* hq = (unsigned char*)(ws + o_hq);
  u16* wb = (u16*)(ws + o_wb);
  float* scaleg = (float*)(ws + o_scale);
  int* counts = (int*)(ws + o_counts);
  int* cursor = (int*)(ws + o_cursor);
  int* offs = (int*)(ws + o_offs);
  unsigned* svc = (unsigned*)(ws + o_svc);

  hipMemsetAsync(counts, 0, 400000, stream);  // counts + cursor

  prep_kernel<<<2048, 256, 0, stream>>>(x, mask, xd, W, wb, rows, counts);
  scan_kernel<<<1, 1024, 0, stream>>>(counts, offs);
  scatter_kernel<<<1563, 256, 0, stream>>>(vals, rows, cols, offs, cursor, svc);
  gemm_kernel<<<391 * 4, 256, 0, stream>>>(xd, wb, hq, scaleg);
  aggregate_kernel<<<12500, 256, 0, stream>>>(hq, scaleg, svc, offs, out);
}

// Round 9
// 403.568 us; speedup vs baseline: 1.4467x; 1.0033x over previous
//
#include <hip/hip_runtime.h>

#define NROWS 50000
#define NFEAT 512
#define NEDGE 1600000
#define SLOPE 0.01f

typedef unsigned short u16;
typedef __attribute__((ext_vector_type(8))) short short8;
typedef __attribute__((ext_vector_type(4))) float f32x4;
typedef __attribute__((ext_vector_type(4))) int i32x4;
typedef __attribute__((ext_vector_type(8))) unsigned short u16x8;

__device__ __forceinline__ u16 f2bf(float f) {
  unsigned u = __float_as_uint(f);
  u += 0x7fffu + ((u >> 16) & 1u);
  return (u16)(u >> 16);
}
__device__ __forceinline__ float lrelu(float v) { return v >= 0.f ? v : SLOPE * v; }

__device__ __forceinline__ void gload_lds16(const u16* g, u16* l) {
  __builtin_amdgcn_global_load_lds((const __attribute__((address_space(1))) void*)g,
                                   (__attribute__((address_space(3))) void*)l, 16, 0, 0);
}

// ---- fused prep: xd = bf16(x*mask), wb = bf16(W), counts = row histogram ----
__global__ void prep_kernel(const float* __restrict__ x, const float* __restrict__ m,
                            u16* __restrict__ xd, const float* __restrict__ w,
                            u16* __restrict__ wb, const int* __restrict__ rows,
                            int* __restrict__ counts) {
  const int stride = gridDim.x * blockDim.x;
  const int tid0 = blockIdx.x * blockDim.x + threadIdx.x;
  for (int i = tid0; i < (NROWS * NFEAT) / 8; i += stride) {
    size_t b = (size_t)i * 2;
    f32x4 a0 = __builtin_nontemporal_load(&((const f32x4*)x)[b]);
    f32x4 a1 = __builtin_nontemporal_load(&((const f32x4*)x)[b + 1]);
    f32x4 m0 = __builtin_nontemporal_load(&((const f32x4*)m)[b]);
    f32x4 m1 = __builtin_nontemporal_load(&((const f32x4*)m)[b + 1]);
    u16x8 o;
    o[0] = f2bf(a0[0] * m0[0]); o[1] = f2bf(a0[1] * m0[1]);
    o[2] = f2bf(a0[2] * m0[2]); o[3] = f2bf(a0[3] * m0[3]);
    o[4] = f2bf(a1[0] * m1[0]); o[5] = f2bf(a1[1] * m1[1]);
    o[6] = f2bf(a1[2] * m1[2]); o[7] = f2bf(a1[3] * m1[3]);
    *(u16x8*)(xd + (size_t)i * 8) = o;
  }
  for (int i = tid0; i < (NFEAT * NFEAT) / 8; i += stride) {
    size_t b = (size_t)i * 2;
    f32x4 a0 = __builtin_nontemporal_load(&((const f32x4*)w)[b]);
    f32x4 a1 = __builtin_nontemporal_load(&((const f32x4*)w)[b + 1]);
    u16x8 o;
    o[0] = f2bf(a0[0]); o[1] = f2bf(a0[1]); o[2] = f2bf(a0[2]); o[3] = f2bf(a0[3]);
    o[4] = f2bf(a1[0]); o[5] = f2bf(a1[1]); o[6] = f2bf(a1[2]); o[7] = f2bf(a1[3]);
    *(u16x8*)(wb + (size_t)i * 8) = o;
  }
  for (int i = tid0; i < NEDGE / 4; i += stride) {
    i32x4 r4 = __builtin_nontemporal_load(&((const i32x4*)rows)[i]);
    atomicAdd(&counts[r4[0]], 1);
    atomicAdd(&counts[r4[1]], 1);
    atomicAdd(&counts[r4[2]], 1);
    atomicAdd(&counts[r4[3]], 1);
  }
}

// ---- scan: CH=64 per thread, int4 loads/stores, shfl wave-scan ----
__global__ void scan_kernel(const int* __restrict__ counts, int* __restrict__ offs) {
  __shared__ int wpre[17];
  const int t = threadIdx.x;            // 1024 threads
  const int lane = t & 63, w = t >> 6;  // 16 waves
  const int beg = t * 64;
  i32x4 c4[16];
  int s = 0;
  if (beg < NROWS) {
#pragma unroll
    for (int g = 0; g < 16; ++g) {
      int idx = beg + g * 4;
      if (idx < NROWS) {
        c4[g] = ((const i32x4*)counts)[idx >> 2];
        s += c4[g][0] + c4[g][1] + c4[g][2] + c4[g][3];
      }
    }
  }
  int inc = s;
#pragma unroll
  for (int d = 1; d < 64; d <<= 1) {
    int u = __shfl_up(inc, d);
    if (lane >= d) inc += u;
  }
  if (lane == 63) wpre[w + 1] = inc;
  __syncthreads();
  if (t == 0) {
    wpre[0] = 0;
    for (int i = 1; i <= 16; ++i) wpre[i] += wpre[i - 1];
    offs[NROWS] = wpre[16];
  }
  __syncthreads();
  int run = wpre[w] + inc - s;
  if (beg < NROWS) {
#pragma unroll
    for (int g = 0; g < 16; ++g) {
      int idx = beg + g * 4;
      if (idx < NROWS) {
        i32x4 o;
        o[0] = run; run += c4[g][0];
        o[1] = run; run += c4[g][1];
        o[2] = run; run += c4[g][2];
        o[3] = run; run += c4[g][3];
        ((i32x4*)offs)[idx >> 2] = o;
      }
    }
  }
}

// ---- scatter: pack (col<<16 | bf16(val)) into u32, 4B random store ----
__global__ void scatter_kernel(const float* __restrict__ vals, const int* __restrict__ rows,
                               const int* __restrict__ cols, const int* __restrict__ offs,
                               int* __restrict__ cursor, unsigned* __restrict__ svc) {
  int e0 = (blockIdx.x * blockDim.x + threadIdx.x) * 4;
  if (e0 >= NEDGE) return;
  i32x4 r4 = __builtin_nontemporal_load((const i32x4*)(rows + e0));
  i32x4 c4 = __builtin_nontemporal_load((const i32x4*)(cols + e0));
  f32x4 v4 = __builtin_nontemporal_load((const f32x4*)(vals + e0));
#pragma unroll
  for (int j = 0; j < 4; ++j) {
    int p = offs[r4[j]] + atomicAdd(&cursor[r4[j]], 1);
    svc[p] = ((unsigned)c4[j] << 16) | (unsigned)f2bf(v4[j]);
  }
}

// ---- GEMM: BK=64, A via swizzled LDS, B DIRECT from global (L2-resident) ----
__global__ __launch_bounds__(256) void gemm_kernel(const u16* __restrict__ xd,
                                                   const u16* __restrict__ wb,
                                                   unsigned char* __restrict__ hq,
                                                   float* __restrict__ scaleg) {
  __shared__ __align__(16) u16 lA[128 * 64];  // 16 KB
  __shared__ float wmax[2][128];
  __shared__ float rinv[128];
  const int tid = threadIdx.x;
  const int lane = tid & 63;
  const int wid = tid >> 6;
  const int wm = wid >> 1, wn = wid & 1;
  // bijective XCD swizzle: nwg = 1564 = 4*196 + 4*195 (q=195, r=4)
  const int bx0 = blockIdx.x;
  const int xcd = bx0 & 7, idx = bx0 >> 3;
  const int wg = (xcd < 4 ? xcd * 196 : 784 + (xcd - 4) * 195) + idx;
  const int tm = wg >> 2;
  const int tn = wg & 3;
  const long rowBase = (long)tm * 128;

  f32x4 acc[4][4] = {};

  const int sl8 = lane >> 3;                 // row within 8-row staging call
  const int scol = ((lane & 7) ^ sl8) * 8;   // pre-swizzled global col (u16 units)
  const int rsel = lane & 15, kgrp = (lane >> 4) * 8;
  const u16* bbase = wb + ((long)(tn * 128 + wn * 64 + rsel)) * 512 + kgrp;

  for (int k0 = 0; k0 < 512; k0 += 64) {
    __syncthreads();
#pragma unroll
    for (int c = 0; c < 4; ++c) {
      int rbase = wid * 32 + c * 8;
      long gr = rowBase + rbase + sl8;
      if (gr > NROWS - 1) gr = NROWS - 1;
      gload_lds16(xd + gr * 512 + k0 + scol, lA + rbase * 64);
    }
    // B fragments direct from global (wb is 512 KB, L2-resident, reused by all M-tiles)
    short8 b[4][2];
#pragma unroll
    for (int n = 0; n < 4; ++n) {
#pragma unroll
      for (int kk = 0; kk < 2; ++kk)
        b[n][kk] = *(const short8*)(bbase + (long)n * 16 * 512 + k0 + kk * 32);
    }
    __syncthreads();
    short8 a[4][2];
#pragma unroll
    for (int m = 0; m < 4; ++m) {
      int ar = wm * 64 + m * 16 + rsel;
      const u16* base = lA + ar * 64;
      int sw = (ar & 7) << 3;
      a[m][0] = *(const short8*)(base + (kgrp ^ sw));
      a[m][1] = *(const short8*)(base + ((32 + kgrp) ^ sw));
    }
#pragma unroll
    for (int kk = 0; kk < 2; ++kk)
#pragma unroll
      for (int m = 0; m < 4; ++m)
#pragma unroll
        for (int n = 0; n < 4; ++n)
          acc[m][n] = __builtin_amdgcn_mfma_f32_16x16x32_bf16(a[m][kk], b[n][kk], acc[m][n], 0, 0, 0);
  }

  // ---- epilogue: per-row max -> scale, int8 quantize, LDS byte-transpose ----
  const int crow = (lane >> 4) * 4;
  const int ccol = lane & 15;

  float pm[4][4];
#pragma unroll
  for (int m = 0; m < 4; ++m)
#pragma unroll
    for (int r2 = 0; r2 < 4; ++r2) {
      float mx = 0.f;
#pragma unroll
      for (int n = 0; n < 4; ++n) mx = fmaxf(mx, fabsf(lrelu(acc[m][n][r2])));
      pm[m][r2] = mx;
    }
#pragma unroll
  for (int d = 1; d < 16; d <<= 1)
#pragma unroll
    for (int m = 0; m < 4; ++m)
#pragma unroll
      for (int r2 = 0; r2 < 4; ++r2) pm[m][r2] = fmaxf(pm[m][r2], __shfl_xor(pm[m][r2], d));
  if ((lane & 15) == 0) {
#pragma unroll
    for (int m = 0; m < 4; ++m)
#pragma unroll
      for (int r2 = 0; r2 < 4; ++r2) wmax[wn][wm * 64 + m * 16 + crow + r2] = pm[m][r2];
  }
  __syncthreads();  // wmax ready AND all waves done reading lA
  if (tid < 128) {
    float rm = fmaxf(wmax[0][tid], wmax[1][tid]);
    float s = rm > 0.f ? rm * (1.f / 127.f) : 1.f;
    rinv[tid] = rm > 0.f ? 127.f / rm : 0.f;
    long gr = rowBase + tid;
    if (gr < NROWS) scaleg[gr * 4 + tn] = s;
  }
  __syncthreads();

  unsigned char* lT = (unsigned char*)lA;  // 128 x 128 int8 tile (16 KB)
#pragma unroll
  for (int m = 0; m < 4; ++m) {
    int row0 = wm * 64 + m * 16 + crow;
    float ri0 = rinv[row0], ri1 = rinv[row0 + 1], ri2 = rinv[row0 + 2], ri3 = rinv[row0 + 3];
#pragma unroll
    for (int n = 0; n < 4; ++n) {
      int col = wn * 64 + n * 16 + ccol;
      float q0 = rintf(lrelu(acc[m][n][0]) * ri0);
      float q1 = rintf(lrelu(acc[m][n][1]) * ri1);
      float q2 = rintf(lrelu(acc[m][n][2]) * ri2);
      float q3 = rintf(lrelu(acc[m][n][3]) * ri3);
      int i0 = min(127, max(-127, (int)q0));
      int i1 = min(127, max(-127, (int)q1));
      int i2 = min(127, max(-127, (int)q2));
      int i3 = min(127, max(-127, (int)q3));
      unsigned pk = (i0 & 0xff) | ((i1 & 0xff) << 8) | ((i2 & 0xff) << 16) | ((i3 & 0xff) << 24);
#pragma unroll
      for (int r2 = 0; r2 < 4; ++r2) {
        int row = row0 + r2;
        lT[row * 128 + (col ^ ((row & 7) << 4))] = (unsigned char)(pk >> (8 * r2));
      }
    }
  }
  __syncthreads();
  {
    const int row = tid >> 1, seg = tid & 1;
    long gr = rowBase + row;
    if (gr < NROWS) {
      unsigned char* dst = hq + gr * 512 + tn * 128;
#pragma unroll
      for (int j = 0; j < 4; ++j) {
        int s = seg * 4 + j;
        i32x4 vv = *(const i32x4*)(lT + row * 128 + ((s ^ (row & 7)) << 4));
        *(i32x4*)(dst + s * 16) = vv;
      }
    }
  }
}

// ---- aggregate: one WAVE per row, 2 edges/wave (32 lanes each), 16B gathers ----
__global__ __launch_bounds__(256) void aggregate_kernel(const unsigned char* __restrict__ hq,
                                                        const float* __restrict__ scaleg,
                                                        const unsigned* __restrict__ svc,
                                                        const int* __restrict__ offs,
                                                        float* __restrict__ out) {
  const int lane = threadIdx.x & 63;
  const int wid = threadIdx.x >> 6;
  const int r = blockIdx.x * 4 + wid;
  if (r >= NROWS) return;
  const int beg = offs[r], end = offs[r + 1];
  const int half = lane >> 5, sub = lane & 31;
  const int grp = sub >> 3;  // 128-col scale block for features sub*16..sub*16+15
  float a[16] = {};
  const unsigned char* hp = hq + sub * 16;
  unsigned cb[4], nb[4];
  const int n = end - beg;
  const int ng = n >> 3;  // groups of 8 edges = 4 per half
  if (ng > 0) {
#pragma unroll
    for (int k = 0; k < 4; ++k) cb[k] = svc[beg + 2 * k + half];
  }
  for (int g = 0; g < ng; ++g) {
    if (g + 1 < ng) {
#pragma unroll
      for (int k = 0; k < 4; ++k) nb[k] = svc[beg + (g + 1) * 8 + 2 * k + half];
    }
#pragma unroll
    for (int k = 0; k < 4; ++k) {
      float v = __uint_as_float(cb[k] << 16);
      size_t c = (size_t)(cb[k] >> 16);
      float vs = v * scaleg[c * 4 + grp];
      i32x4 q = *(const i32x4*)(hp + c * 512);
#pragma unroll
      for (int j = 0; j < 4; ++j) {
        unsigned qq = (unsigned)q[j];
        a[4 * j + 0] += vs * (float)(signed char)(qq);
        a[4 * j + 1] += vs * (float)(signed char)(qq >> 8);
        a[4 * j + 2] += vs * (float)(signed char)(qq >> 16);
        a[4 * j + 3] += vs * (float)(signed char)(qq >> 24);
      }
    }
    if (g + 1 < ng) {
#pragma unroll
      for (int k = 0; k < 4; ++k) cb[k] = nb[k];
    }
  }
  int e = beg + ng * 8;
  for (; e + 1 < end; e += 2) {  // remaining pairs, both halves active
    unsigned u = svc[e + half];
    float v = __uint_as_float(u << 16);
    size_t c = (size_t)(u >> 16);
    float vs = v * scaleg[c * 4 + grp];
    i32x4 q = *(const i32x4*)(hp + c * 512);
#pragma unroll
    for (int j = 0; j < 4; ++j) {
      unsigned qq = (unsigned)q[j];
      a[4 * j + 0] += vs * (float)(signed char)(qq);
      a[4 * j + 1] += vs * (float)(signed char)(qq >> 8);
      a[4 * j + 2] += vs * (float)(signed char)(qq >> 16);
      a[4 * j + 3] += vs * (float)(signed char)(qq >> 24);
    }
  }
  if (e < end) {  // odd final edge: only half 0 contributes
    unsigned u = svc[e];
    float v = __uint_as_float(u << 16);
    size_t c = (size_t)(u >> 16);
    float vs = half ? 0.f : v * scaleg[c * 4 + grp];
    i32x4 q = *(const i32x4*)(hp + c * 512);
#pragma unroll
    for (int j = 0; j < 4; ++j) {
      unsigned qq = (unsigned)q[j];
      a[4 * j + 0] += vs * (float)(signed char)(qq);
      a[4 * j + 1] += vs * (float)(signed char)(qq >> 8);
      a[4 * j + 2] += vs * (float)(signed char)(qq >> 16);
      a[4 * j + 3] += vs * (float)(signed char)(qq >> 24);
    }
  }
  // merge the two halves
#pragma unroll
  for (int j = 0; j < 16; ++j) a[j] += __shfl_xor(a[j], 32);
  if (half == 0) {
    float* op = out + (size_t)r * NFEAT + sub * 16;
#pragma unroll
    for (int j = 0; j < 4; ++j) {
      f32x4 o;
      o[0] = lrelu(a[4 * j + 0]);
      o[1] = lrelu(a[4 * j + 1]);
      o[2] = lrelu(a[4 * j + 2]);
      o[3] = lrelu(a[4 * j + 3]);
      *(f32x4*)(op + 4 * j) = o;
    }
  }
}

extern "C" void kernel_launch(void* const* d_in, const int* in_sizes, int n_in,
                              void* d_out, int out_size, void* d_ws, size_t ws_size,
                              hipStream_t stream) {
  const float* x = (const float*)d_in[0];
  const float* W = (const float*)d_in[1];
  const float* mask = (const float*)d_in[2];
  const float* vals = (const float*)d_in[3];
  const int* rows = (const int*)d_in[4];
  const int* cols = (const int*)d_in[5];
  float* out = (float*)d_out;
  char* ws = (char*)d_ws;

  const size_t o_xd = 0;                       // 51,200,000 (bf16 x*mask)
  const size_t o_hq = o_xd + 51200000;         // 25,600,000 (int8 h)
  const size_t o_wb = o_hq + 25600000;         // 524,288
  const size_t o_scale = o_wb + 524288;        // 800,000 (f32 scale[row][4])
  const size_t o_counts = o_scale + 800000;    // 200,000
  const size_t o_cursor = o_counts + 200000;   // 200,000
  const size_t o_offs = o_cursor + 200000;     // 200,064
  const size_t o_svc = o_offs + 200064;        // 6,400,000 (u32 packed col|bf16val)

  u16* xd = (u16*)(ws + o_xd);
  unsigned char* hq = (unsigned char*)(ws + o_hq);
  u16* wb = (u16*)(ws + o_wb);
  float* scaleg = (float*)(ws + o_scale);
  int* counts = (int*)(ws + o_counts);
  int* cursor = (int*)(ws + o_cursor);
  int* offs = (int*)(ws + o_offs);
  unsigned* svc = (unsigned*)(ws + o_svc);

  hipMemsetAsync(counts, 0, 400000, stream);  // counts + cursor

  prep_kernel<<<2048, 256, 0, stream>>>(x, mask, xd, W, wb, rows, counts);
  scan_kernel<<<1, 1024, 0, stream>>>(counts, offs);
  scatter_kernel<<<1563, 256, 0, stream>>>(vals, rows, cols, offs, cursor, svc);
  gemm_kernel<<<391 * 4, 256, 0, stream>>>(xd, wb, hq, scaleg);
  aggregate_kernel<<<12500, 256, 0, stream>>>(hq, scaleg, svc, offs, out);
}